// Round 1
// baseline (5363.452 us; speedup 1.0000x reference)
//
#include <hip/hip_runtime.h>
#include <math.h>

#define B_    8
#define L_    2000
#define V_    50000
#define E_    300
#define NL_   8922
#define LW_   10
#define F_    200
#define KW_   10
#define H_    200
#define FEAT_ 500
#define LP_   1991   // L - K + 1

// ---------------------------------------------------------------------------
// avg[n][e] = sum_w we[lidx[n][w]][e]*lmask / sum_w lmask ; also transposed copy
__global__ __launch_bounds__(256) void k_avg(const float* __restrict__ we,
                                             const int* __restrict__ lidx,
                                             const float* __restrict__ lmask,
                                             float* __restrict__ avg,
                                             float* __restrict__ avgT) {
  int idx = blockIdx.x * 256 + threadIdx.x;
  if (idx >= NL_ * E_) return;
  int n = idx / E_, e = idx - n * E_;
  float s = 0.f, ms = 0.f;
#pragma unroll
  for (int w = 0; w < LW_; ++w) {
    float mw = lmask[n * LW_ + w];
    s = fmaf(we[(size_t)lidx[n * LW_ + w] * E_ + e], mw, s);
    ms += mw;
  }
  float v = s / ms;
  avg[idx] = v;
  avgT[(size_t)e * NL_ + n] = v;
}

// ---------------------------------------------------------------------------
// agg[n] = (adj[n,:] @ avg) / num_neighbors[n]   (sparse row scan, ~18 nnz)
__global__ __launch_bounds__(256) void k_agg(const float* __restrict__ adj,
                                             const float* __restrict__ avg,
                                             const float* __restrict__ nnb,
                                             float* __restrict__ agg) {
  __shared__ int s_idx[1024];
  __shared__ float s_val[1024];
  __shared__ int s_cnt;
  const int n = blockIdx.x;
  const int tid = threadIdx.x;
  if (tid == 0) s_cnt = 0;
  __syncthreads();
  const float* row = adj + (size_t)n * NL_;
  for (int j = tid; j < NL_; j += 256) {
    float v = row[j];
    if (v != 0.f) {
      int p = atomicAdd(&s_cnt, 1);
      if (p < 1024) { s_idx[p] = j; s_val[p] = v; }
    }
  }
  __syncthreads();
  const int m = min(s_cnt, 1024);
  const float inv = 1.f / nnb[n];
  float a0 = 0.f, a1 = 0.f;
  for (int i = 0; i < m; ++i) {
    const float* ar = avg + (size_t)s_idx[i] * E_;
    float v = s_val[i];
    a0 = fmaf(v, ar[tid], a0);
    if (tid < E_ - 256) a1 = fmaf(v, ar[tid + 256], a1);
  }
  agg[(size_t)n * E_ + tid] = a0 * inv;
  if (tid < E_ - 256) agg[(size_t)n * E_ + tid + 256] = a1 * inv;
}

// ---------------------------------------------------------------------------
// gh[n][h] = relu(agg[n,:] @ Wg[:,h] + bg[h]);  8 labels per block
__global__ __launch_bounds__(256) void k_gh(const float* __restrict__ agg,
                                            const float* __restrict__ Wg,
                                            const float* __restrict__ bg,
                                            float* __restrict__ gh) {
  __shared__ float s_agg[2400];  // [e][8]
  const int n0 = blockIdx.x * 8;
  const int tid = threadIdx.x;
  for (int i = tid; i < 2400; i += 256) {
    int e = i >> 3, nn = i & 7;
    int n = n0 + nn;
    s_agg[i] = (n < NL_) ? agg[(size_t)n * E_ + e] : 0.f;
  }
  __syncthreads();
  if (tid < H_) {
    const int h = tid;
    float bb = bg[h];
    float acc[8];
#pragma unroll
    for (int i = 0; i < 8; ++i) acc[i] = bb;
    for (int e = 0; e < E_; ++e) {
      float w = Wg[(size_t)e * H_ + h];
      float4 a0 = *(const float4*)&s_agg[e * 8];
      float4 a1 = *(const float4*)&s_agg[e * 8 + 4];
      acc[0] = fmaf(a0.x, w, acc[0]); acc[1] = fmaf(a0.y, w, acc[1]);
      acc[2] = fmaf(a0.z, w, acc[2]); acc[3] = fmaf(a0.w, w, acc[3]);
      acc[4] = fmaf(a1.x, w, acc[4]); acc[5] = fmaf(a1.y, w, acc[5]);
      acc[6] = fmaf(a1.z, w, acc[6]); acc[7] = fmaf(a1.w, w, acc[7]);
    }
#pragma unroll
    for (int i = 0; i < 8; ++i) {
      int n = n0 + i;
      if (n < NL_) gh[(size_t)n * H_ + h] = fmaxf(acc[i], 0.f);
    }
  }
}

// ---------------------------------------------------------------------------
// xe[b][l][e] = we[x[b][l]][e] * mask[b][l]
__global__ __launch_bounds__(256) void k_xe(const int* __restrict__ x,
                                            const float* __restrict__ mask,
                                            const float* __restrict__ we,
                                            float* __restrict__ xe) {
  size_t idx = (size_t)blockIdx.x * 256 + threadIdx.x;
  if (idx >= (size_t)B_ * L_ * E_) return;
  size_t bl = idx / E_;
  int e = (int)(idx - bl * E_);
  xe[idx] = we[(size_t)x[bl] * E_ + e] * mask[bl];
}

// ---------------------------------------------------------------------------
// Wct3[k][e][f] = Wc[f][e][k]
__global__ __launch_bounds__(256) void k_wct(const float* __restrict__ Wc,
                                             float* __restrict__ Wct3) {
  int idx = blockIdx.x * 256 + threadIdx.x;
  if (idx >= KW_ * E_ * F_) return;
  int k = idx / (E_ * F_);
  int r = idx - k * (E_ * F_);
  int e = r / F_, f = r - e * F_;
  Wct3[idx] = Wc[((size_t)f * E_ + e) * KW_ + k];
}

// ---------------------------------------------------------------------------
// conv: c[b][l][f] = relu(sum_{e,k} xe[b][l+k][e]*Wc[f][e][k] + bc[f])
// lane = l (64-tile), wave owns contiguous 50 f's -> Wc via wave-uniform s_load
__global__ __launch_bounds__(256) void k_conv(const float* __restrict__ xe,
                                              const float* __restrict__ Wct3,
                                              const float* __restrict__ bc,
                                              float* __restrict__ cmat) {
  __shared__ float s_xe[150 * 73];  // [e_local][l_row]
  const int b = blockIdx.y;
  const int l0 = blockIdx.x * 64;
  const int tid = threadIdx.x;
  const int lane = tid & 63;
  const int wv = tid >> 6;  // 0..3 -> f block = wv*50
  float acc[50];
#pragma unroll
  for (int j = 0; j < 50; ++j) acc[j] = 0.f;
  for (int ep = 0; ep < 2; ++ep) {
    const int e0 = ep * 150;
    __syncthreads();
    for (int i = tid; i < 73 * 150; i += 256) {
      int r = i / 150, e = i - r * 150;
      int l = l0 + r;
      s_xe[e * 73 + r] = (l < L_) ? xe[((size_t)b * L_ + l) * E_ + (e0 + e)] : 0.f;
    }
    __syncthreads();
    for (int e = 0; e < 150; ++e) {
      const int eg = e0 + e;
#pragma unroll
      for (int k = 0; k < KW_; ++k) {
        float xv = s_xe[e * 73 + lane + k];
        int sbase = __builtin_amdgcn_readfirstlane((k * E_ + eg) * F_ + wv * 50);
        const float* wr = Wct3 + sbase;
#pragma unroll
        for (int j = 0; j < 50; ++j) acc[j] = fmaf(xv, wr[j], acc[j]);
      }
    }
  }
  const int l = l0 + lane;
  if (l < LP_) {
    float* crow = cmat + ((size_t)b * LP_ + l) * F_ + wv * 50;
#pragma unroll
    for (int j = 0; j < 50; ++j) crow[j] = fmaxf(acc[j] + bc[wv * 50 + j], 0.f);
  }
}

// ---------------------------------------------------------------------------
// pjT[b][e][l] = tanh(sum_f c[b][l][f]*Wp[f][e] + bp[e])   (stored transposed, pitch 2048)
__global__ __launch_bounds__(256) void k_pj(const float* __restrict__ cmat,
                                            const float* __restrict__ Wp,
                                            const float* __restrict__ bp,
                                            float* __restrict__ pjT) {
  __shared__ float s_c[12800];  // [f][64] xor-swizzled columns
  const int b = blockIdx.y;
  const int l0 = blockIdx.x * 64;
  const int tid = threadIdx.x;
  for (int i = tid; i < 64 * F_; i += 256) {
    int l = i / F_, f = i - l * F_;
    int lg = l0 + l;
    float v = (lg < LP_) ? cmat[((size_t)b * LP_ + lg) * F_ + f] : 0.f;
    s_c[f * 64 + (l ^ ((f & 7) << 2))] = v;
  }
  __syncthreads();
  const int tl = tid & 15, te = tid >> 4;
  for (int jc = 0; jc < 5; ++jc) {
    float acc[4][4];
#pragma unroll
    for (int jj = 0; jj < 4; ++jj)
#pragma unroll
      for (int m = 0; m < 4; ++m) acc[jj][m] = 0.f;
    int ev[4]; bool vj[4];
#pragma unroll
    for (int jj = 0; jj < 4; ++jj) {
      int j = jc * 4 + jj;
      int e = te + 16 * j;
      vj[jj] = (j < 19) && (e < E_);
      ev[jj] = vj[jj] ? e : 0;
    }
    for (int f = 0; f < F_; ++f) {
      float4 c4 = *(const float4*)&s_c[f * 64 + ((tl * 4) ^ ((f & 7) << 2))];
      float cv[4] = {c4.x, c4.y, c4.z, c4.w};
#pragma unroll
      for (int jj = 0; jj < 4; ++jj) {
        float w = vj[jj] ? Wp[(size_t)f * E_ + ev[jj]] : 0.f;
#pragma unroll
        for (int m = 0; m < 4; ++m) acc[jj][m] = fmaf(cv[m], w, acc[jj][m]);
      }
    }
#pragma unroll
    for (int jj = 0; jj < 4; ++jj) {
      if (vj[jj]) {
        int e = ev[jj];
        float bpe = bp[e];
#pragma unroll
        for (int m = 0; m < 4; ++m) {
          int lg = l0 + tl * 4 + m;
          if (lg < LP_) pjT[((size_t)b * E_ + e) * 2048 + lg] = tanhf(acc[jj][m] + bpe);
        }
      }
    }
  }
}

// ---------------------------------------------------------------------------
// Fused label-wise attention + proj + logits. Block = (b, 32 labels).
// Flash-style online softmax over l-chunks of 128.
__global__ __launch_bounds__(256, 3) void k_attn(
    const float* __restrict__ pjT, const float* __restrict__ cmat,
    const float* __restrict__ avgT, const float* __restrict__ avg,
    const float* __restrict__ gh, const float* __restrict__ Wo,
    const float* __restrict__ bo, float* __restrict__ out) {
  __shared__ float s_buf[6400];   // pj stage [50][128] / c stage [32][200] / aoT [200][32]
  __shared__ float s_avg[1600];   // avg chunk [50][32]
  __shared__ float s_p[4096];     // scores/probs [128][32]
  __shared__ float s_m[32], s_s[32], s_r[32], s_logit[32];

  const int tid = threadIdx.x;
  const int bid = blockIdx.x;
  const int b = bid & 7;               // XCD-locality swizzle
  const int n0 = (bid >> 3) << 5;

  if (tid < 32) { s_m[tid] = -1e30f; s_s[tid] = 0.f; s_logit[tid] = 0.f; }

  const int tl5 = tid & 31, tn8 = tid >> 5;       // score tiling 4l x 4n
  const int tq = tid % 25, tn4b = tid / 25;       // O tiling 4n x 8f (tid<200)
  const bool oact = (tid < 200);

  float o[4][8];
#pragma unroll
  for (int i = 0; i < 4; ++i)
#pragma unroll
    for (int j = 0; j < 8; ++j) o[i][j] = 0.f;

  const float* pjTb = pjT + (size_t)b * (E_ * 2048);
  const float* cb = cmat + (size_t)b * LP_ * F_;

  for (int lc = 0; lc < 16; ++lc) {
    const int l_base = lc << 7;
    const int lcount = min(128, LP_ - l_base);

    float acc[4][4];
#pragma unroll
    for (int m = 0; m < 4; ++m)
#pragma unroll
      for (int j = 0; j < 4; ++j) acc[m][j] = 0.f;

    for (int ec = 0; ec < 6; ++ec) {
      const int e0 = ec * 50;
      __syncthreads();
      for (int i4 = tid; i4 < 1600; i4 += 256) {
        int e = i4 >> 5, l4 = i4 & 31;
        *(float4*)&s_buf[e * 128 + l4 * 4] =
            *(const float4*)&pjTb[(size_t)(e0 + e) * 2048 + l_base + l4 * 4];
      }
      for (int i = tid; i < 1600; i += 256) {
        int e = i >> 5, nl = i & 31;
        int ng = n0 + nl;
        s_avg[i] = (ng < NL_) ? avgT[(size_t)(e0 + e) * NL_ + ng] : 0.f;
      }
      __syncthreads();
      for (int e = 0; e < 50; ++e) {
        float4 pq = *(const float4*)&s_buf[e * 128 + tl5 * 4];
        float4 aq = *(const float4*)&s_avg[e * 32 + tn8 * 4];
        float pv[4] = {pq.x, pq.y, pq.z, pq.w};
        float av[4] = {aq.x, aq.y, aq.z, aq.w};
#pragma unroll
        for (int m = 0; m < 4; ++m)
#pragma unroll
          for (int j = 0; j < 4; ++j) acc[m][j] = fmaf(pv[m], av[j], acc[m][j]);
      }
    }
    __syncthreads();
#pragma unroll
    for (int m = 0; m < 4; ++m) {
      float4 v = {acc[m][0], acc[m][1], acc[m][2], acc[m][3]};
      *(float4*)&s_p[(tl5 * 4 + m) * 32 + tn8 * 4] = v;
    }
    __syncthreads();
    if (tid < 32) {
      const int n = tid;
      float mo = s_m[n];
      float cm = -1e30f;
      for (int l = 0; l < lcount; ++l) cm = fmaxf(cm, s_p[l * 32 + n]);
      float nm = fmaxf(mo, cm);
      float r = __expf(mo - nm);
      float ps = 0.f;
      for (int l = 0; l < lcount; ++l) {
        float p = __expf(s_p[l * 32 + n] - nm);
        s_p[l * 32 + n] = p;
        ps += p;
      }
      for (int l = lcount; l < 128; ++l) s_p[l * 32 + n] = 0.f;
      s_s[n] = s_s[n] * r + ps;
      s_m[n] = nm;
      s_r[n] = r;
    }
    __syncthreads();
    if (oact) {
#pragma unroll
      for (int jn = 0; jn < 4; ++jn) {
        float rr = s_r[tn4b * 4 + jn];
#pragma unroll
        for (int jj = 0; jj < 8; ++jj) o[jn][jj] *= rr;
      }
    }
    for (int sub = 0; sub < 4; ++sub) {
      __syncthreads();
      for (int i4 = tid; i4 < 1600; i4 += 256) {
        int l = i4 / 50, q = i4 - l * 50;
        int lg = l_base + sub * 32 + l;
        float4 v = {0.f, 0.f, 0.f, 0.f};
        if (lg < LP_) v = *(const float4*)&cb[(size_t)lg * F_ + q * 4];
        *(float4*)&s_buf[l * 200 + q * 4] = v;
      }
      __syncthreads();
      if (oact) {
        for (int l = 0; l < 32; ++l) {
          float4 p4 = *(const float4*)&s_p[(sub * 32 + l) * 32 + tn4b * 4];
          float4 c0 = *(const float4*)&s_buf[l * 200 + tq * 4];
          float4 c1 = *(const float4*)&s_buf[l * 200 + (tq + 25) * 4];
          float pv[4] = {p4.x, p4.y, p4.z, p4.w};
          float cv[8] = {c0.x, c0.y, c0.z, c0.w, c1.x, c1.y, c1.z, c1.w};
#pragma unroll
          for (int jn = 0; jn < 4; ++jn)
#pragma unroll
            for (int jj = 0; jj < 8; ++jj)
              o[jn][jj] = fmaf(pv[jn], cv[jj], o[jn][jj]);
        }
      }
    }
  }
  __syncthreads();
  if (oact) {
#pragma unroll
    for (int jn = 0; jn < 4; ++jn) {
      float iv = 1.f / s_s[tn4b * 4 + jn];
#pragma unroll
      for (int jj = 0; jj < 8; ++jj) o[jn][jj] *= iv;
    }
#pragma unroll
    for (int cc = 0; cc < 4; ++cc) {
      float4 v0 = {o[0][cc], o[1][cc], o[2][cc], o[3][cc]};
      *(float4*)&s_buf[(tq * 4 + cc) * 32 + tn4b * 4] = v0;
      float4 v1 = {o[0][4 + cc], o[1][4 + cc], o[2][4 + cc], o[3][4 + cc]};
      *(float4*)&s_buf[((tq + 25) * 4 + cc) * 32 + tn4b * 4] = v1;
    }
  }
  __syncthreads();
  {
    const int tfp = tid & 15, tnp = tid >> 4;
    float lp[2] = {0.f, 0.f};
    for (int fc = 0; fc < 4; ++fc) {
      const int fb0 = fc * 128 + tfp * 8;
      const int fb1 = fb0 + 4;
      const bool v0 = fb0 < FEAT_, v1 = fb1 < FEAT_;
      float ap[2][8];
#pragma unroll
      for (int t = 0; t < 4; ++t) {
        float b0 = v0 ? bo[fb0 + t] : 0.f;
        float b1 = v1 ? bo[fb1 + t] : 0.f;
        ap[0][t] = b0; ap[1][t] = b0;
        ap[0][4 + t] = b1; ap[1][4 + t] = b1;
      }
      for (int f = 0; f < F_; ++f) {
        float2 ao = *(const float2*)&s_buf[f * 32 + tnp * 2];
        float4 w0 = v0 ? *(const float4*)&Wo[(size_t)f * FEAT_ + fb0] : make_float4(0.f, 0.f, 0.f, 0.f);
        float4 w1 = v1 ? *(const float4*)&Wo[(size_t)f * FEAT_ + fb1] : make_float4(0.f, 0.f, 0.f, 0.f);
        float wv[8] = {w0.x, w0.y, w0.z, w0.w, w1.x, w1.y, w1.z, w1.w};
        float an[2] = {ao.x, ao.y};
#pragma unroll
        for (int jn = 0; jn < 2; ++jn)
#pragma unroll
          for (int t = 0; t < 8; ++t) ap[jn][t] = fmaf(an[jn], wv[t], ap[jn][t]);
      }
#pragma unroll
      for (int jn = 0; jn < 2; ++jn) {
        const int ng = n0 + tnp * 2 + jn;
        if (ng < NL_) {
#pragma unroll
          for (int t = 0; t < 8; ++t) {
            const bool vv = (t < 4) ? v0 : v1;
            if (vv) {
              const int feat = (t < 4) ? (fb0 + t) : (fb1 + t - 4);
              float p = fmaxf(ap[jn][t], 0.f);
              float ge = (feat < E_) ? avg[(size_t)ng * E_ + feat]
                                     : gh[(size_t)ng * H_ + (feat - E_)];
              lp[jn] = fmaf(p, ge, lp[jn]);
            }
          }
        }
      }
    }
    atomicAdd(&s_logit[tnp * 2 + 0], lp[0]);
    atomicAdd(&s_logit[tnp * 2 + 1], lp[1]);
  }
  __syncthreads();
  if (tid < 32) {
    const int ng = n0 + tid;
    if (ng < NL_) out[(size_t)b * NL_ + ng] = s_logit[tid];
  }
}

// ---------------------------------------------------------------------------
// BCE-with-logits sum / B  (single block)
__global__ __launch_bounds__(1024) void k_loss(const float* __restrict__ lgts,
                                               const float* __restrict__ y,
                                               float* __restrict__ loss) {
  __shared__ float red[1024];
  const int tid = threadIdx.x;
  float s = 0.f;
  for (int i = tid; i < B_ * NL_; i += 1024) {
    float l = lgts[i], yy = y[i];
    s += fmaxf(l, 0.f) - l * yy + log1pf(expf(-fabsf(l)));
  }
  red[tid] = s;
  __syncthreads();
  for (int st = 512; st > 0; st >>= 1) {
    if (tid < st) red[tid] += red[tid + st];
    __syncthreads();
  }
  if (tid == 0) loss[0] = red[0] * (1.f / B_);
}

// ---------------------------------------------------------------------------
extern "C" void kernel_launch(void* const* d_in, const int* in_sizes, int n_in,
                              void* d_out, int out_size, void* d_ws, size_t ws_size,
                              hipStream_t stream) {
  const int*   x     = (const int*)  d_in[0];
  const float* y     = (const float*)d_in[1];
  const float* mask  = (const float*)d_in[2];
  const float* we    = (const float*)d_in[3];
  const int*   lidx  = (const int*)  d_in[4];
  const float* lmask = (const float*)d_in[5];
  const float* adj   = (const float*)d_in[6];
  const float* nnb   = (const float*)d_in[7];
  const float* Wg    = (const float*)d_in[8];
  const float* bg    = (const float*)d_in[9];
  const float* Wc    = (const float*)d_in[10];
  const float* bc    = (const float*)d_in[11];
  const float* Wp    = (const float*)d_in[12];
  const float* bp    = (const float*)d_in[13];
  const float* Wo    = (const float*)d_in[14];
  const float* bo    = (const float*)d_in[15];
  float* out = (float*)d_out;
  float* ws = (float*)d_ws;

  // ws layout (floats). sbuf is time-shared: agg -> xe -> pjT (sequential deps).
  float* sbuf = ws;                     // 4,915,200 (= B*E*2048, >= agg 2.68M, xe 4.8M)
  float* avg  = sbuf + 4915200;         // 2,676,600
  float* avgT = avg + 2676600;          // 2,676,600
  float* gh   = avgT + 2676600;         // 1,784,400
  float* Wct3 = gh + 1784400;           //   600,000
  float* cmat = Wct3 + 600000;          // 3,185,600
  float* agg = sbuf;
  float* xe  = sbuf;
  float* pjT = sbuf;

  k_avg<<<(NL_ * E_ + 255) / 256, 256, 0, stream>>>(we, lidx, lmask, avg, avgT);
  k_agg<<<NL_, 256, 0, stream>>>(adj, avg, nnb, agg);
  k_gh<<<(NL_ + 7) / 8, 256, 0, stream>>>(agg, Wg, bg, gh);
  k_xe<<<(B_ * L_ * E_ + 255) / 256, 256, 0, stream>>>(x, mask, we, xe);
  k_wct<<<(KW_ * E_ * F_ + 255) / 256, 256, 0, stream>>>(Wc, Wct3);
  k_conv<<<dim3(32, B_), 256, 0, stream>>>(xe, Wct3, bc, cmat);
  k_pj<<<dim3(32, B_), 256, 0, stream>>>(cmat, Wp, bp, pjT);
  k_attn<<<279 * 8, 256, 0, stream>>>(pjT, cmat, avgT, avg, gh, Wo, bo, out);
  k_loss<<<1, 1024, 0, stream>>>(out, y, out + B_ * NL_);
}

// Round 2
// 3026.900 us; speedup vs baseline: 1.7719x; 1.7719x over previous
//
#include <hip/hip_runtime.h>
#include <math.h>

#define B_    8
#define L_    2000
#define V_    50000
#define E_    300
#define NL_   8922
#define LW_   10
#define F_    200
#define KW_   10
#define H_    200
#define FEAT_ 500
#define LP_   1991   // L - K + 1

typedef __attribute__((ext_vector_type(8))) short bf16x8;
typedef __attribute__((ext_vector_type(4))) float f32x4;

static __device__ __forceinline__ float b2f(unsigned short u) {
  unsigned v = ((unsigned)u) << 16;
  return __builtin_bit_cast(float, v);
}
static __device__ __forceinline__ unsigned short f2b(float f) {
  unsigned u = __builtin_bit_cast(unsigned, f);
  u += 0x7FFF + ((u >> 16) & 1);   // round-to-nearest-even
  return (unsigned short)(u >> 16);
}

// ---------------------------------------------------------------------------
// avg over label-desc words -> avg fp32 [n][300], ge[n][512] (first 300), bf16 [n][320] (e-padded 0)
__global__ __launch_bounds__(256) void k_avg(const float* __restrict__ we,
                                             const int* __restrict__ lidx,
                                             const float* __restrict__ lmask,
                                             float* __restrict__ avg,
                                             unsigned short* __restrict__ avgb,
                                             float* __restrict__ ge) {
  int idx = blockIdx.x * 256 + threadIdx.x;
  if (idx >= NL_ * 320) return;
  int n = idx / 320, e = idx - n * 320;
  if (e >= E_) { avgb[(size_t)n * 320 + e] = 0; return; }
  float s = 0.f, ms = 0.f;
#pragma unroll
  for (int w = 0; w < LW_; ++w) {
    float mw = lmask[n * LW_ + w];
    s = fmaf(we[(size_t)lidx[n * LW_ + w] * E_ + e], mw, s);
    ms += mw;
  }
  float v = s / ms;
  avg[(size_t)n * E_ + e] = v;
  ge[(size_t)n * 512 + e] = v;
  avgb[(size_t)n * 320 + e] = f2b(v);
}

// ---------------------------------------------------------------------------
// agg[n] = (adj[n,:] @ avg) / num_neighbors[n]   (sparse row scan)
__global__ __launch_bounds__(256) void k_agg(const float* __restrict__ adj,
                                             const float* __restrict__ avg,
                                             const float* __restrict__ nnb,
                                             float* __restrict__ agg) {
  __shared__ int s_idx[1024];
  __shared__ float s_val[1024];
  __shared__ int s_cnt;
  const int n = blockIdx.x;
  const int tid = threadIdx.x;
  if (tid == 0) s_cnt = 0;
  __syncthreads();
  const float* row = adj + (size_t)n * NL_;
  for (int j = tid; j < NL_; j += 256) {
    float v = row[j];
    if (v != 0.f) {
      int p = atomicAdd(&s_cnt, 1);
      if (p < 1024) { s_idx[p] = j; s_val[p] = v; }
    }
  }
  __syncthreads();
  const int m = min(s_cnt, 1024);
  const float inv = 1.f / nnb[n];
  float a0 = 0.f, a1 = 0.f;
  for (int i = 0; i < m; ++i) {
    const float* ar = avg + (size_t)s_idx[i] * E_;
    float v = s_val[i];
    a0 = fmaf(v, ar[tid], a0);
    if (tid < E_ - 256) a1 = fmaf(v, ar[tid + 256], a1);
  }
  agg[(size_t)n * E_ + tid] = a0 * inv;
  if (tid < E_ - 256) agg[(size_t)n * E_ + tid + 256] = a1 * inv;
}

// ---------------------------------------------------------------------------
// gh -> ge[n][300..499] = relu(agg @ Wg + bg);  zero-pad ge[n][500..511]
__global__ __launch_bounds__(256) void k_gh(const float* __restrict__ agg,
                                            const float* __restrict__ Wg,
                                            const float* __restrict__ bg,
                                            float* __restrict__ ge) {
  __shared__ float s_agg[2400];  // [e][8]
  const int n0 = blockIdx.x * 8;
  const int tid = threadIdx.x;
  for (int i = tid; i < 2400; i += 256) {
    int e = i >> 3, nn = i & 7;
    int n = n0 + nn;
    s_agg[i] = (n < NL_) ? agg[(size_t)n * E_ + e] : 0.f;
  }
  __syncthreads();
  if (tid < 96) {  // zero pad feat 500..511
    int nn = tid / 12, c = tid - nn * 12;
    int n = n0 + nn;
    if (n < NL_) ge[(size_t)n * 512 + 500 + c] = 0.f;
  }
  if (tid < H_) {
    const int h = tid;
    float bb = bg[h];
    float acc[8];
#pragma unroll
    for (int i = 0; i < 8; ++i) acc[i] = bb;
    for (int e = 0; e < E_; ++e) {
      float w = Wg[(size_t)e * H_ + h];
      float4 a0 = *(const float4*)&s_agg[e * 8];
      float4 a1 = *(const float4*)&s_agg[e * 8 + 4];
      acc[0] = fmaf(a0.x, w, acc[0]); acc[1] = fmaf(a0.y, w, acc[1]);
      acc[2] = fmaf(a0.z, w, acc[2]); acc[3] = fmaf(a0.w, w, acc[3]);
      acc[4] = fmaf(a1.x, w, acc[4]); acc[5] = fmaf(a1.y, w, acc[5]);
      acc[6] = fmaf(a1.z, w, acc[6]); acc[7] = fmaf(a1.w, w, acc[7]);
    }
#pragma unroll
    for (int i = 0; i < 8; ++i) {
      int n = n0 + i;
      if (n < NL_) ge[(size_t)n * 512 + 300 + h] = fmaxf(acc[i], 0.f);
    }
  }
}

// ---------------------------------------------------------------------------
// Wct3[k][e][f] = Wc[f][e][k]  (fp32, for the fp32 conv)
__global__ __launch_bounds__(256) void k_wct(const float* __restrict__ Wc,
                                             float* __restrict__ Wct3) {
  int idx = blockIdx.x * 256 + threadIdx.x;
  if (idx >= KW_ * E_ * F_) return;
  int k = idx / (E_ * F_);
  int r = idx - k * (E_ * F_);
  int e = r / F_, f = r - e * F_;
  Wct3[idx] = Wc[((size_t)f * E_ + e) * KW_ + k];
}

// ---------------------------------------------------------------------------
// WoT[feat][f] = Wo[f][feat] bf16, zero-padded to [512][224]
__global__ __launch_bounds__(256) void k_wot(const float* __restrict__ Wo,
                                             unsigned short* __restrict__ WoT) {
  int idx = blockIdx.x * 256 + threadIdx.x;
  if (idx >= 512 * 224) return;
  int ft = idx / 224, f = idx - ft * 224;
  float v = (ft < FEAT_ && f < F_) ? Wo[(size_t)f * FEAT_ + ft] : 0.f;
  WoT[idx] = f2b(v);
}

// ---------------------------------------------------------------------------
// conv (gathers word_emb directly): cT[b][f][l(2048)] = bf16(relu(conv))
__global__ __launch_bounds__(256) void k_conv(const int* __restrict__ x,
                                              const float* __restrict__ mask,
                                              const float* __restrict__ we,
                                              const float* __restrict__ Wct3,
                                              const float* __restrict__ bc,
                                              unsigned short* __restrict__ cT) {
  __shared__ float s_xe[150 * 73];  // [e_local][l_row]
  const int b = blockIdx.y;
  const int l0 = blockIdx.x * 64;
  const int tid = threadIdx.x;
  const int lane = tid & 63;
  const int wv = tid >> 6;  // f block = wv*50
  float acc[50];
#pragma unroll
  for (int j = 0; j < 50; ++j) acc[j] = 0.f;
  for (int ep = 0; ep < 2; ++ep) {
    const int e0 = ep * 150;
    __syncthreads();
    for (int i = tid; i < 73 * 150; i += 256) {
      int r = i / 150, e = i - r * 150;
      int l = l0 + r;
      float v = 0.f;
      if (l < L_) {
        int bl = b * L_ + l;
        v = we[(size_t)x[bl] * E_ + e0 + e] * mask[bl];
      }
      s_xe[e * 73 + r] = v;
    }
    __syncthreads();
    for (int e = 0; e < 150; ++e) {
      const int eg = e0 + e;
#pragma unroll
      for (int k = 0; k < KW_; ++k) {
        float xv = s_xe[e * 73 + lane + k];
        int sbase = __builtin_amdgcn_readfirstlane((k * E_ + eg) * F_ + wv * 50);
        const float* wr = Wct3 + sbase;
#pragma unroll
        for (int j = 0; j < 50; ++j) acc[j] = fmaf(xv, wr[j], acc[j]);
      }
    }
  }
  const int l = l0 + lane;
  if (l < LP_) {
#pragma unroll
    for (int j = 0; j < 50; ++j)
      cT[((size_t)b * F_ + wv * 50 + j) * 2048 + l] = f2b(fmaxf(acc[j] + bc[wv * 50 + j], 0.f));
  }
}

// ---------------------------------------------------------------------------
// pj[b][l(2048)][320] bf16 = tanh(c @ Wp + bp); reads cT bf16, LDS-transposed output
__global__ __launch_bounds__(256) void k_pj(const unsigned short* __restrict__ cT,
                                            const float* __restrict__ Wp,
                                            const float* __restrict__ bp,
                                            unsigned short* __restrict__ pj) {
  __shared__ unsigned short s_c[200 * 72];   // [f][l] 28800 B
  __shared__ unsigned short s_o[64 * 312];   // [l][e] 39936 B
  const int b = blockIdx.y;
  const int l0 = blockIdx.x * 64;
  const int tid = threadIdx.x;
  for (int i = tid; i < 200 * 16; i += 256) {
    int f = i >> 4, c4 = i & 15;
    *(ushort4*)&s_c[f * 72 + c4 * 4] =
        *(const ushort4*)&cT[((size_t)b * F_ + f) * 2048 + l0 + c4 * 4];
  }
  __syncthreads();
  const int tl = tid & 15, te = tid >> 4;
  for (int j = 0; j < 19; ++j) {
    int e = te + 16 * j;
    if (e >= E_) break;
    float a0 = 0.f, a1 = 0.f, a2 = 0.f, a3 = 0.f;
    for (int f = 0; f < F_; ++f) {
      float w = Wp[(size_t)f * E_ + e];
      ushort4 cv = *(const ushort4*)&s_c[f * 72 + tl * 4];
      a0 = fmaf(b2f(cv.x), w, a0);
      a1 = fmaf(b2f(cv.y), w, a1);
      a2 = fmaf(b2f(cv.z), w, a2);
      a3 = fmaf(b2f(cv.w), w, a3);
    }
    float bpe = bp[e];
    s_o[(tl * 4 + 0) * 312 + e] = f2b(tanhf(a0 + bpe));
    s_o[(tl * 4 + 1) * 312 + e] = f2b(tanhf(a1 + bpe));
    s_o[(tl * 4 + 2) * 312 + e] = f2b(tanhf(a2 + bpe));
    s_o[(tl * 4 + 3) * 312 + e] = f2b(tanhf(a3 + bpe));
  }
  __syncthreads();
  for (int i = tid; i < 64 * 75; i += 256) {
    int r = i / 75, c4 = i - r * 75;
    *(ushort4*)&pj[((size_t)b * 2048 + l0 + r) * 320 + c4 * 4] =
        *(const ushort4*)&s_o[r * 312 + c4 * 4];
  }
}

// ---------------------------------------------------------------------------
// Fused flash attention + proj + logits, MFMA bf16. Block = (b, 32 labels).
__global__ __launch_bounds__(256, 2) void k_attn(
    const unsigned short* __restrict__ pj,    // [8][2048][320]
    const unsigned short* __restrict__ cT,    // [8][200][2048]
    const unsigned short* __restrict__ avgb,  // [NL][320]
    const unsigned short* __restrict__ WoT,   // [512][224]
    const float* __restrict__ ge,             // [NL][512]
    const float* __restrict__ bo,
    float* __restrict__ out) {
  __shared__ __attribute__((aligned(16))) unsigned char smem[59904];
  unsigned short* s_avg = (unsigned short*)smem;            // [32][328] 20992 B persistent
  unsigned short* s_pj  = (unsigned short*)(smem + 20992);  // [128][72] 18432 B (phase A)
  unsigned short* s_P   = (unsigned short*)(smem + 20992);  // [32][136] alias (phase C->E)
  float*          s_S   = (float*)(smem + 39424);           // [32][132] fp32 (phase B->C)
  unsigned short* s_c   = (unsigned short*)(smem + 39424);  // [224][40] alias (phase E)
  unsigned short* s_AO  = (unsigned short*)(smem + 39424);  // [32][232] alias (epilogue)
  float* s_red  = (float*)(smem + 57344);
  float* s_red2 = (float*)(smem + 58368);
  float* s_m    = (float*)(smem + 59392);
  float* s_sum  = (float*)(smem + 59520);
  float* s_r    = (float*)(smem + 59648);
  float* s_lg   = (float*)(smem + 59776);

  const int tid = threadIdx.x;
  const int b  = blockIdx.x & 7;
  const int n0 = (blockIdx.x >> 3) << 5;
  const int wv = tid >> 6, lane = tid & 63, quad = lane >> 4, c16 = lane & 15;
  const int nt2 = wv >> 1, fh = wv & 1;

  if (tid < 32) { s_m[tid] = -3.0e38f; s_sum[tid] = 0.f; s_lg[tid] = 0.f; }

  // stage avg (persistent)
  for (int i = tid; i < 2560; i += 256) {
    int n = i / 80, c4 = i - n * 80;
    int ng = n0 + n;
    ushort4 v = make_ushort4(0, 0, 0, 0);
    if (ng < NL_) v = *(const ushort4*)&avgb[(size_t)ng * 320 + c4 * 4];
    *(ushort4*)&s_avg[n * 328 + c4 * 4] = v;
  }

  const unsigned short* pjb = pj + (size_t)b * (2048 * 320);
  const unsigned short* cTb = cT + (size_t)b * (F_ * 2048);

  f32x4 o[7];
#pragma unroll
  for (int i = 0; i < 7; ++i) o[i] = (f32x4){0.f, 0.f, 0.f, 0.f};

  for (int lc = 0; lc < 16; ++lc) {
    const int l_base = lc << 7;
    f32x4 accs[2][2];
#pragma unroll
    for (int mt = 0; mt < 2; ++mt)
#pragma unroll
      for (int nt = 0; nt < 2; ++nt) accs[mt][nt] = (f32x4){0.f, 0.f, 0.f, 0.f};

    // ---- scores: S[l][n] += pj[l][e] * avg[n][e] ----
    for (int es = 0; es < 5; ++es) {
      const int e0 = es * 64;
      __syncthreads();
      for (int i = tid; i < 2048; i += 256) {
        int l = i >> 4, c4 = i & 15;
        *(ushort4*)&s_pj[l * 72 + c4 * 4] =
            *(const ushort4*)&pjb[(size_t)(l_base + l) * 320 + e0 + c4 * 4];
      }
      __syncthreads();
#pragma unroll
      for (int ks = 0; ks < 2; ++ks) {
        const int ko = ks * 32 + quad * 8;
        bf16x8 a0 = *(const bf16x8*)&s_pj[(wv * 32 + c16) * 72 + ko];
        bf16x8 a1 = *(const bf16x8*)&s_pj[(wv * 32 + 16 + c16) * 72 + ko];
        bf16x8 b0 = *(const bf16x8*)&s_avg[c16 * 328 + e0 + ko];
        bf16x8 b1 = *(const bf16x8*)&s_avg[(16 + c16) * 328 + e0 + ko];
        accs[0][0] = __builtin_amdgcn_mfma_f32_16x16x32_bf16(a0, b0, accs[0][0], 0, 0, 0);
        accs[0][1] = __builtin_amdgcn_mfma_f32_16x16x32_bf16(a0, b1, accs[0][1], 0, 0, 0);
        accs[1][0] = __builtin_amdgcn_mfma_f32_16x16x32_bf16(a1, b0, accs[1][0], 0, 0, 0);
        accs[1][1] = __builtin_amdgcn_mfma_f32_16x16x32_bf16(a1, b1, accs[1][1], 0, 0, 0);
      }
    }
    // ---- write scores to s_S [n][l] ----
#pragma unroll
    for (int mt = 0; mt < 2; ++mt)
#pragma unroll
      for (int nt = 0; nt < 2; ++nt) {
        int lrow = wv * 32 + mt * 16 + quad * 4;
        int ncol = nt * 16 + c16;
#pragma unroll
        for (int r = 0; r < 4; ++r) s_S[ncol * 132 + lrow + r] = accs[mt][nt][r];
      }
    __syncthreads();
    // ---- online softmax (per label row) ----
    {
      const int n = tid >> 3, j = tid & 7;
      const int lmax = min(128, LP_ - l_base);
      float mloc = -3.0e38f;
      for (int ii = 0; ii < 16; ++ii) {
        int l = j * 16 + ii;
        if (l < lmax) mloc = fmaxf(mloc, s_S[n * 132 + l]);
      }
      s_red[tid] = mloc;
      __syncthreads();
      float mrow = s_red[n * 8];
      for (int t = 1; t < 8; ++t) mrow = fmaxf(mrow, s_red[n * 8 + t]);
      float mold = s_m[n];
      float mnew = fmaxf(mold, mrow);
      float psum = 0.f;
      for (int ii = 0; ii < 16; ++ii) {
        int l = j * 16 + ii;
        float p = 0.f;
        if (l < lmax) p = __expf(s_S[n * 132 + l] - mnew);
        s_P[n * 136 + l] = f2b(p);
        psum += p;
      }
      s_red2[tid] = psum;
      __syncthreads();
      if (j == 0) {
        float tot = 0.f;
        for (int t = 0; t < 8; ++t) tot += s_red2[n * 8 + t];
        float rr = __expf(mold - mnew);
        s_sum[n] = s_sum[n] * rr + tot;
        s_m[n] = mnew;
        s_r[n] = rr;
      }
    }
    __syncthreads();
    // ---- rescale O, then PV: O[n][f] += P[n][l] * cT[f][l] ----
    {
      float rr4[4];
#pragma unroll
      for (int r = 0; r < 4; ++r) rr4[r] = s_r[nt2 * 16 + quad * 4 + r];
#pragma unroll
      for (int ft = 0; ft < 7; ++ft) {
        o[ft][0] *= rr4[0]; o[ft][1] *= rr4[1]; o[ft][2] *= rr4[2]; o[ft][3] *= rr4[3];
      }
    }
    for (int sub = 0; sub < 4; ++sub) {
      __syncthreads();
      for (int i = tid; i < 1792; i += 256) {
        int f = i >> 3, c4 = i & 7;
        ushort4 v = make_ushort4(0, 0, 0, 0);
        if (f < F_) v = *(const ushort4*)&cTb[(size_t)f * 2048 + l_base + sub * 32 + c4 * 4];
        *(ushort4*)&s_c[f * 40 + c4 * 4] = v;
      }
      __syncthreads();
      const int ko = quad * 8;
      bf16x8 ap = *(const bf16x8*)&s_P[(nt2 * 16 + c16) * 136 + sub * 32 + ko];
#pragma unroll
      for (int ft = 0; ft < 7; ++ft) {
        bf16x8 bp8 = *(const bf16x8*)&s_c[((fh * 7 + ft) * 16 + c16) * 40 + ko];
        o[ft] = __builtin_amdgcn_mfma_f32_16x16x32_bf16(ap, bp8, o[ft], 0, 0, 0);
      }
    }
  }

  // ---- epilogue: normalize, attn_out -> s_AO bf16 (A-layout) ----
  __syncthreads();
  {
    float inv4[4];
#pragma unroll
    for (int r = 0; r < 4; ++r) inv4[r] = 1.f / s_sum[nt2 * 16 + quad * 4 + r];
#pragma unroll
    for (int ft = 0; ft < 7; ++ft) {
      int f = (fh * 7 + ft) * 16 + c16;
#pragma unroll
      for (int r = 0; r < 4; ++r)
        s_AO[(nt2 * 16 + quad * 4 + r) * 232 + f] = f2b(o[ft][r] * inv4[r]);
    }
  }
  __syncthreads();
  // ---- proj: P2[n][feat] = AO[n][f] * WoT[feat][f], feat tiles per wave ----
  f32x4 pa[2][8];
#pragma unroll
  for (int nt = 0; nt < 2; ++nt)
#pragma unroll
    for (int i = 0; i < 8; ++i) pa[nt][i] = (f32x4){0.f, 0.f, 0.f, 0.f};
  for (int ks = 0; ks < 7; ++ks) {
    const int ko = ks * 32 + quad * 8;
    bf16x8 a0 = *(const bf16x8*)&s_AO[c16 * 232 + ko];
    bf16x8 a1 = *(const bf16x8*)&s_AO[(16 + c16) * 232 + ko];
#pragma unroll
    for (int i = 0; i < 8; ++i) {
      int fr = wv * 128 + i * 16 + c16;
      bf16x8 bw = *(const bf16x8*)&WoT[(size_t)fr * 224 + ko];
      pa[0][i] = __builtin_amdgcn_mfma_f32_16x16x32_bf16(a0, bw, pa[0][i], 0, 0, 0);
      pa[1][i] = __builtin_amdgcn_mfma_f32_16x16x32_bf16(a1, bw, pa[1][i], 0, 0, 0);
    }
  }
  // ---- relu + dot with graph_emb, reduce to logits ----
  float la[2][4];
#pragma unroll
  for (int nt = 0; nt < 2; ++nt)
#pragma unroll
    for (int r = 0; r < 4; ++r) la[nt][r] = 0.f;
  for (int i = 0; i < 8; ++i) {
    int feat = wv * 128 + i * 16 + c16;
    bool fok = feat < FEAT_;
    float bof = fok ? bo[feat] : 0.f;
#pragma unroll
    for (int nt = 0; nt < 2; ++nt) {
#pragma unroll
      for (int r = 0; r < 4; ++r) {
        int ng = n0 + nt * 16 + quad * 4 + r;
        float pv = fmaxf(pa[nt][i][r] + bof, 0.f);
        float gv = (fok && ng < NL_) ? ge[(size_t)ng * 512 + feat] : 0.f;
        la[nt][r] = fmaf(pv, gv, la[nt][r]);
      }
    }
  }
#pragma unroll
  for (int nt = 0; nt < 2; ++nt)
#pragma unroll
    for (int r = 0; r < 4; ++r) {
      float v = la[nt][r];
      v += __shfl_xor(v, 1); v += __shfl_xor(v, 2);
      v += __shfl_xor(v, 4); v += __shfl_xor(v, 8);
      if (c16 == 0) atomicAdd(&s_lg[nt * 16 + quad * 4 + r], v);
    }
  __syncthreads();
  if (tid < 32) {
    int ng = n0 + tid;
    if (ng < NL_) out[(size_t)b * NL_ + ng] = s_lg[tid];
  }
}

// ---------------------------------------------------------------------------
__global__ __launch_bounds__(1024) void k_loss(const float* __restrict__ lgts,
                                               const float* __restrict__ y,
                                               float* __restrict__ loss) {
  __shared__ float red[1024];
  const int tid = threadIdx.x;
  float s = 0.f;
  for (int i = tid; i < B_ * NL_; i += 1024) {
    float l = lgts[i], yy = y[i];
    s += fmaxf(l, 0.f) - l * yy + log1pf(expf(-fabsf(l)));
  }
  red[tid] = s;
  __syncthreads();
  for (int st = 512; st > 0; st >>= 1) {
    if (tid < st) red[tid] += red[tid + st];
    __syncthreads();
  }
  if (tid == 0) loss[0] = red[0] * (1.f / B_);
}

// ---------------------------------------------------------------------------
extern "C" void kernel_launch(void* const* d_in, const int* in_sizes, int n_in,
                              void* d_out, int out_size, void* d_ws, size_t ws_size,
                              hipStream_t stream) {
  const int*   x     = (const int*)  d_in[0];
  const float* y     = (const float*)d_in[1];
  const float* mask  = (const float*)d_in[2];
  const float* we    = (const float*)d_in[3];
  const int*   lidx  = (const int*)  d_in[4];
  const float* lmask = (const float*)d_in[5];
  const float* adj   = (const float*)d_in[6];
  const float* nnb   = (const float*)d_in[7];
  const float* Wg    = (const float*)d_in[8];
  const float* bg    = (const float*)d_in[9];
  const float* Wc    = (const float*)d_in[10];
  const float* bc    = (const float*)d_in[11];
  const float* Wp    = (const float*)d_in[12];
  const float* bp    = (const float*)d_in[13];
  const float* Wo    = (const float*)d_in[14];
  const float* bo    = (const float*)d_in[15];
  float* out = (float*)d_out;
  char* W = (char*)d_ws;

  // ws layout (bytes, 16-aligned). agg aliases pj/cT (dead before conv/pj run).
  unsigned short* pj   = (unsigned short*)(W + 0);          // 10,485,760
  unsigned short* cT   = (unsigned short*)(W + 10485760);   //  6,553,600
  float*          avg  = (float*)(W + 17039360);            // 10,706,400
  unsigned short* avgb = (unsigned short*)(W + 27745760);   //  5,710,080
  float*          ge   = (float*)(W + 33455840);            // 18,272,256
  float*          Wct3 = (float*)(W + 51728096);            //  2,400,000
  unsigned short* WoT  = (unsigned short*)(W + 54128096);   //    229,376 (end 54,357,472)
  float*          agg  = (float*)(W + 0);

  k_avg<<<(NL_ * 320 + 255) / 256, 256, 0, stream>>>(we, lidx, lmask, avg, avgb, ge);
  k_agg<<<NL_, 256, 0, stream>>>(adj, avg, nnb, agg);
  k_gh<<<(NL_ + 7) / 8, 256, 0, stream>>>(agg, Wg, bg, ge);
  k_wct<<<(KW_ * E_ * F_ + 255) / 256, 256, 0, stream>>>(Wc, Wct3);
  k_wot<<<(512 * 224 + 255) / 256, 256, 0, stream>>>(Wo, WoT);
  k_conv<<<dim3(32, B_), 256, 0, stream>>>(x, mask, we, Wct3, bc, cT);
  k_pj<<<dim3(32, B_), 256, 0, stream>>>(cT, Wp, bp, pj);
  k_attn<<<279 * 8, 256, 0, stream>>>(pj, cT, avgb, WoT, ge, bo, out);
  k_loss<<<1, 1024, 0, stream>>>(out, y, out + B_ * NL_);
}

// Round 3
// 1570.225 us; speedup vs baseline: 3.4157x; 1.9277x over previous
//
#include <hip/hip_runtime.h>
#include <math.h>

#define B_    8
#define L_    2000
#define V_    50000
#define E_    300
#define NL_   8922
#define NLP_  8928   // padded label count (multiple of 32)
#define LW_   10
#define F_    200
#define KW_   10
#define H_    200
#define FEAT_ 500
#define LP_   1991   // L - K + 1

typedef __attribute__((ext_vector_type(8))) short bf16x8;
typedef __attribute__((ext_vector_type(4))) float f32x4;

static __device__ __forceinline__ unsigned short f2b(float f) {
  unsigned u = __builtin_bit_cast(unsigned, f);
  u += 0x7FFF + ((u >> 16) & 1);   // round-to-nearest-even
  return (unsigned short)(u >> 16);
}

#define MFMA(a, b, c) __builtin_amdgcn_mfma_f32_16x16x32_bf16(a, b, c, 0, 0, 0)

// ---------------------------------------------------------------------------
// label-desc average: ge[n][0..299] fp32, avgb[n][320] bf16 (zero-padded rows/cols)
__global__ __launch_bounds__(256) void k_avg(const float* __restrict__ we,
                                             const int* __restrict__ lidx,
                                             const float* __restrict__ lmask,
                                             unsigned short* __restrict__ avgb,
                                             float* __restrict__ ge) {
  int idx = blockIdx.x * 256 + threadIdx.x;
  if (idx >= NLP_ * 80) return;
  int n = idx / 80, e4 = idx - n * 80;
  if (n >= NL_ || e4 >= 75) {
    *(ushort4*)&avgb[(size_t)n * 320 + e4 * 4] = make_ushort4(0, 0, 0, 0);
    return;
  }
  float ax = 0.f, ay = 0.f, az = 0.f, aw = 0.f, ms = 0.f;
#pragma unroll
  for (int w = 0; w < LW_; ++w) {
    float mw = lmask[n * LW_ + w];
    const float4 f = *(const float4*)&we[(size_t)lidx[n * LW_ + w] * E_ + e4 * 4];
    ax = fmaf(f.x, mw, ax); ay = fmaf(f.y, mw, ay);
    az = fmaf(f.z, mw, az); aw = fmaf(f.w, mw, aw);
    ms += mw;
  }
  float inv = 1.f / ms;
  float4 v = {ax * inv, ay * inv, az * inv, aw * inv};
  *(float4*)&ge[(size_t)n * 512 + e4 * 4] = v;
  *(ushort4*)&avgb[(size_t)n * 320 + e4 * 4] =
      make_ushort4(f2b(v.x), f2b(v.y), f2b(v.z), f2b(v.w));
}

// ---------------------------------------------------------------------------
// agg[n] = (adj[n,:] @ avg) / num_neighbors[n]  (sparse scan; avg read from ge rows)
__global__ __launch_bounds__(256) void k_agg(const float* __restrict__ adj,
                                             const float* __restrict__ ge,
                                             const float* __restrict__ nnb,
                                             float* __restrict__ agg) {
  __shared__ int s_idx[1024];
  __shared__ float s_val[1024];
  __shared__ int s_cnt;
  const int n = blockIdx.x;
  const int tid = threadIdx.x;
  if (tid == 0) s_cnt = 0;
  __syncthreads();
  const float* row = adj + (size_t)n * NL_;
  for (int j = tid; j < NL_; j += 256) {
    float v = row[j];
    if (v != 0.f) {
      int p = atomicAdd(&s_cnt, 1);
      if (p < 1024) { s_idx[p] = j; s_val[p] = v; }
    }
  }
  __syncthreads();
  const int m = min(s_cnt, 1024);
  const float inv = 1.f / nnb[n];
  float a0 = 0.f, a1 = 0.f;
  for (int i = 0; i < m; ++i) {
    const float* ar = ge + (size_t)s_idx[i] * 512;
    float v = s_val[i];
    a0 = fmaf(v, ar[tid], a0);
    if (tid < E_ - 256) a1 = fmaf(v, ar[tid + 256], a1);
  }
  agg[(size_t)n * E_ + tid] = a0 * inv;
  if (tid < E_ - 256) agg[(size_t)n * E_ + tid + 256] = a1 * inv;
}

// ---------------------------------------------------------------------------
// ge[n][300..499] = relu(agg @ Wg + bg); zero-pad ge[n][500..511]
__global__ __launch_bounds__(256) void k_gh(const float* __restrict__ agg,
                                            const float* __restrict__ Wg,
                                            const float* __restrict__ bg,
                                            float* __restrict__ ge) {
  __shared__ float s_agg[2400];  // [e][8]
  const int n0 = blockIdx.x * 8;
  const int tid = threadIdx.x;
  for (int i = tid; i < 2400; i += 256) {
    int e = i >> 3, nn = i & 7;
    int n = n0 + nn;
    s_agg[i] = (n < NL_) ? agg[(size_t)n * E_ + e] : 0.f;
  }
  __syncthreads();
  if (tid < 96) {
    int nn = tid / 12, c = tid - nn * 12;
    int n = n0 + nn;
    if (n < NL_) ge[(size_t)n * 512 + 500 + c] = 0.f;
  }
  if (tid < H_) {
    const int h = tid;
    float bb = bg[h];
    float acc[8];
#pragma unroll
    for (int i = 0; i < 8; ++i) acc[i] = bb;
    for (int e = 0; e < E_; ++e) {
      float w = Wg[(size_t)e * H_ + h];
      float4 a0 = *(const float4*)&s_agg[e * 8];
      float4 a1 = *(const float4*)&s_agg[e * 8 + 4];
      acc[0] = fmaf(a0.x, w, acc[0]); acc[1] = fmaf(a0.y, w, acc[1]);
      acc[2] = fmaf(a0.z, w, acc[2]); acc[3] = fmaf(a0.w, w, acc[3]);
      acc[4] = fmaf(a1.x, w, acc[4]); acc[5] = fmaf(a1.y, w, acc[5]);
      acc[6] = fmaf(a1.z, w, acc[6]); acc[7] = fmaf(a1.w, w, acc[7]);
    }
#pragma unroll
    for (int i = 0; i < 8; ++i) {
      int n = n0 + i;
      if (n < NL_) ge[(size_t)n * 512 + 300 + h] = fmaxf(acc[i], 0.f);
    }
  }
}

// ---------------------------------------------------------------------------
// WcT[k][f(256)][e(320)] = bf16(Wc[f][e][k]), zero pad
__global__ __launch_bounds__(256) void k_wct(const float* __restrict__ Wc,
                                             unsigned short* __restrict__ WcT) {
  int idx = blockIdx.x * 256 + threadIdx.x;
  if (idx >= KW_ * 256 * 320) return;
  int k = idx / (256 * 320);
  int r = idx - k * (256 * 320);
  int f = r / 320, e = r - f * 320;
  float v = (f < F_ && e < E_) ? Wc[((size_t)f * E_ + e) * KW_ + k] : 0.f;
  WcT[idx] = f2b(v);
}

// ---------------------------------------------------------------------------
// WpT[e(320)][f(224)] = bf16(Wp[f][e]), zero pad
__global__ __launch_bounds__(256) void k_wpt(const float* __restrict__ Wp,
                                             unsigned short* __restrict__ WpT) {
  int idx = blockIdx.x * 256 + threadIdx.x;
  if (idx >= 320 * 224) return;
  int e = idx / 224, f = idx - e * 224;
  float v = (e < E_ && f < F_) ? Wp[(size_t)f * E_ + e] : 0.f;
  WpT[idx] = f2b(v);
}

// ---------------------------------------------------------------------------
// WoT[feat(512)][f(224)] = bf16(Wo[f][feat]), zero pad
__global__ __launch_bounds__(256) void k_wot(const float* __restrict__ Wo,
                                             unsigned short* __restrict__ WoT) {
  int idx = blockIdx.x * 256 + threadIdx.x;
  if (idx >= 512 * 224) return;
  int ft = idx / 224, f = idx - ft * 224;
  float v = (ft < FEAT_ && f < F_) ? Wo[(size_t)f * FEAT_ + ft] : 0.f;
  WoT[idx] = f2b(v);
}

// ---------------------------------------------------------------------------
// Fused conv + pj, MFMA bf16. Block = (64 l) x b. 256 blocks.
// conv: c[l][f] = relu(sum_k sum_e xe[l+k][e] WcT[k][f][e] + bc)
// pj:   pj[l][e] = tanh(sum_f c[l][f] WpT[e][f] + bp)
__global__ __launch_bounds__(256) void k_cpj(const int* __restrict__ x,
                                             const float* __restrict__ mask,
                                             const float* __restrict__ we,
                                             const unsigned short* __restrict__ WcT,
                                             const float* __restrict__ bc,
                                             const unsigned short* __restrict__ WpT,
                                             const float* __restrict__ bp,
                                             unsigned short* __restrict__ cT,
                                             unsigned short* __restrict__ pjo) {
  __shared__ unsigned short s_xe[73 * 328 + 8];  // [row][e(328)] bf16
  __shared__ unsigned short s_cA[64 * 232];      // [l][f(232)] bf16
  const int b = blockIdx.y;
  const int l0 = blockIdx.x * 64;
  const int tid = threadIdx.x;
  const int wv = tid >> 6, lane = tid & 63, quad = lane >> 4, c16 = lane & 15;

  // ---- stage xe (gather + bf16) ----
  for (int i = tid; i < 73 * 75; i += 256) {
    int row = i / 75, e4 = i - row * 75;
    int l = l0 + row;
    float4 v = {0.f, 0.f, 0.f, 0.f};
    if (l < L_) {
      int bl = b * L_ + l;
      v = *(const float4*)&we[(size_t)x[bl] * E_ + e4 * 4];
      float mm = mask[bl];
      v.x *= mm; v.y *= mm; v.z *= mm; v.w *= mm;
    }
    *(ushort4*)&s_xe[row * 328 + e4 * 4] =
        make_ushort4(f2b(v.x), f2b(v.y), f2b(v.z), f2b(v.w));
  }
  for (int i = tid; i < 73 * 7; i += 256) {
    int row = i / 7, c = i - row * 7;
    *(ushort4*)&s_xe[row * 328 + 300 + c * 4] = make_ushort4(0, 0, 0, 0);
  }
  for (int i = tid; i < 64 * 8; i += 256) {
    int row = i >> 3, c = i & 7;
    *(ushort4*)&s_cA[row * 232 + 200 + c * 4] = make_ushort4(0, 0, 0, 0);
  }
  __syncthreads();

  // ---- conv GEMM: 4 m-tiles x 4 f-tiles per wave ----
  f32x4 acc[4][4];
#pragma unroll
  for (int mt = 0; mt < 4; ++mt)
#pragma unroll
    for (int j = 0; j < 4; ++j) acc[mt][j] = (f32x4){0.f, 0.f, 0.f, 0.f};
  for (int koff = 0; koff < KW_; ++koff) {
#pragma unroll
    for (int ks = 0; ks < 10; ++ks) {
      bf16x8 a[4];
#pragma unroll
      for (int mt = 0; mt < 4; ++mt)
        a[mt] = *(const bf16x8*)&s_xe[(mt * 16 + c16 + koff) * 328 + ks * 32 + quad * 8];
#pragma unroll
      for (int j = 0; j < 4; ++j) {
        int f = (wv * 4 + j) * 16 + c16;
        bf16x8 bw = *(const bf16x8*)&WcT[((size_t)koff * 256 + f) * 320 + ks * 32 + quad * 8];
#pragma unroll
        for (int mt = 0; mt < 4; ++mt) acc[mt][j] = MFMA(a[mt], bw, acc[mt][j]);
      }
    }
  }
  // ---- conv epilogue: bias+relu, write s_cA + cT ----
#pragma unroll
  for (int j = 0; j < 4; ++j) {
    int f = (wv * 4 + j) * 16 + c16;
    if (f < F_) {
      float bcv = bc[f];
#pragma unroll
      for (int mt = 0; mt < 4; ++mt) {
        unsigned short u[4];
#pragma unroll
        for (int r = 0; r < 4; ++r) u[r] = f2b(fmaxf(acc[mt][j][r] + bcv, 0.f));
        int ll = mt * 16 + quad * 4;
#pragma unroll
        for (int r = 0; r < 4; ++r) s_cA[(ll + r) * 232 + f] = u[r];
        int lg = l0 + ll;
        unsigned short* dst = &cT[((size_t)b * 224 + f) * 2048 + lg];
        if (lg + 3 < LP_) {
          *(ushort4*)dst = make_ushort4(u[0], u[1], u[2], u[3]);
        } else {
#pragma unroll
          for (int r = 0; r < 4; ++r)
            if (lg + r < LP_) dst[r] = u[r];
        }
      }
    }
  }
  __syncthreads();

  // ---- pj GEMM: 4 m-tiles x 5 e-tiles per wave, K = 224 ----
  f32x4 pacc[4][5];
#pragma unroll
  for (int mt = 0; mt < 4; ++mt)
#pragma unroll
    for (int j = 0; j < 5; ++j) pacc[mt][j] = (f32x4){0.f, 0.f, 0.f, 0.f};
#pragma unroll
  for (int ks = 0; ks < 7; ++ks) {
    bf16x8 a[4];
#pragma unroll
    for (int mt = 0; mt < 4; ++mt)
      a[mt] = *(const bf16x8*)&s_cA[(mt * 16 + c16) * 232 + ks * 32 + quad * 8];
#pragma unroll
    for (int j = 0; j < 5; ++j) {
      int e = (wv * 5 + j) * 16 + c16;
      bf16x8 bw = *(const bf16x8*)&WpT[(size_t)e * 224 + ks * 32 + quad * 8];
#pragma unroll
      for (int mt = 0; mt < 4; ++mt) pacc[mt][j] = MFMA(a[mt], bw, pacc[mt][j]);
    }
  }
  // ---- pj epilogue: tanh, transpose via LDS (reuse s_xe), store ----
  unsigned short* s_po = s_xe;
#pragma unroll
  for (int j = 0; j < 5; ++j) {
    int e = (wv * 5 + j) * 16 + c16;
    if (e < E_) {
      float bpe = bp[e];
#pragma unroll
      for (int mt = 0; mt < 4; ++mt)
#pragma unroll
        for (int r = 0; r < 4; ++r)
          s_po[(mt * 16 + quad * 4 + r) * 328 + e] = f2b(tanhf(pacc[mt][j][r] + bpe));
    }
  }
  __syncthreads();
  for (int i = tid; i < 64 * 80; i += 256) {
    int row = i / 80, c4 = i - row * 80;
    ushort4 u = make_ushort4(0, 0, 0, 0);
    if (c4 < 75) u = *(const ushort4*)&s_po[row * 328 + c4 * 4];
    *(ushort4*)&pjo[((size_t)b * 2048 + l0 + row) * 320 + c4 * 4] = u;
  }
}

// ---------------------------------------------------------------------------
// Fused flash attention + proj + logits. Block = (b, 32 labels). 3 barriers/chunk.
__global__ __launch_bounds__(256, 3) void k_attn(
    const unsigned short* __restrict__ pj,    // [8][2048][320]
    const unsigned short* __restrict__ cT,    // [8][224][2048]
    const unsigned short* __restrict__ avgb,  // [8928][320]
    const unsigned short* __restrict__ WoT,   // [512][224]
    const float* __restrict__ ge,             // [NL][512]
    const float* __restrict__ bo,
    float* __restrict__ out) {
  __shared__ __attribute__((aligned(16))) unsigned char smem[16384];
  unsigned short* s_P  = (unsigned short*)smem;           // [32][136] (scores phase)
  unsigned short* s_AO = (unsigned short*)smem;           // [32][232] (epilogue alias)
  float* s_wmax = (float*)(smem + 14848);  // [4][32]
  float* s_wsum = (float*)(smem + 15360);  // [4][32]
  float* s_m    = (float*)(smem + 15872);  // [32]
  float* s_sum  = (float*)(smem + 16000);  // [32]
  float* s_r    = (float*)(smem + 16128);  // [32]
  float* s_lg   = (float*)(smem + 16256);  // [32]

  const int tid = threadIdx.x;
  const int b  = blockIdx.x & 7;           // XCD-locality swizzle
  const int n0 = (blockIdx.x >> 3) << 5;
  const int wv = tid >> 6, lane = tid & 63, quad = lane >> 4, c16 = lane & 15;
  const int nt2 = wv >> 1, fh = wv & 1;

  if (tid < 32) { s_m[tid] = -3.0e38f; s_sum[tid] = 0.f; s_lg[tid] = 0.f; }

  // avg B-fragments resident in registers (80 VGPRs)
  bf16x8 bavg[10][2];
#pragma unroll
  for (int ks = 0; ks < 10; ++ks)
#pragma unroll
    for (int nt = 0; nt < 2; ++nt)
      bavg[ks][nt] =
          *(const bf16x8*)&avgb[(size_t)(n0 + nt * 16 + c16) * 320 + ks * 32 + quad * 8];

  const unsigned short* pjb = pj + (size_t)b * (2048 * 320);
  const unsigned short* cTb = cT + (size_t)b * (224 * 2048);

  f32x4 o[7];
#pragma unroll
  for (int i = 0; i < 7; ++i) o[i] = (f32x4){0.f, 0.f, 0.f, 0.f};

  for (int lc = 0; lc < 16; ++lc) {
    const int l_base = lc << 7;
    // ---- scores in registers: A from global, B from regs ----
    f32x4 accs[2][2];
#pragma unroll
    for (int mt = 0; mt < 2; ++mt)
#pragma unroll
      for (int nt = 0; nt < 2; ++nt) accs[mt][nt] = (f32x4){0.f, 0.f, 0.f, 0.f};
    {
      const unsigned short* pr0 =
          pjb + (size_t)(l_base + wv * 32 + c16) * 320 + quad * 8;
      const unsigned short* pr1 = pr0 + 16 * 320;
#pragma unroll
      for (int ks = 0; ks < 10; ++ks) {
        bf16x8 a0 = *(const bf16x8*)(pr0 + ks * 32);
        bf16x8 a1 = *(const bf16x8*)(pr1 + ks * 32);
        accs[0][0] = MFMA(a0, bavg[ks][0], accs[0][0]);
        accs[0][1] = MFMA(a0, bavg[ks][1], accs[0][1]);
        accs[1][0] = MFMA(a1, bavg[ks][0], accs[1][0]);
        accs[1][1] = MFMA(a1, bavg[ks][1], accs[1][1]);
      }
    }
    // ---- in-register online softmax ----
#pragma unroll
    for (int nt = 0; nt < 2; ++nt) {
      float v = -3.0e38f;
#pragma unroll
      for (int mt = 0; mt < 2; ++mt) {
        int lb = l_base + wv * 32 + mt * 16 + quad * 4;
#pragma unroll
        for (int r = 0; r < 4; ++r)
          if (lb + r < LP_) v = fmaxf(v, accs[mt][nt][r]);
      }
      v = fmaxf(v, __shfl_xor(v, 16));
      v = fmaxf(v, __shfl_xor(v, 32));
      if (lane < 16) s_wmax[wv * 32 + nt * 16 + lane] = v;
    }
    __syncthreads();  // barrier 1
#pragma unroll
    for (int nt = 0; nt < 2; ++nt) {
      const int n = nt * 16 + c16;
      float mw = fmaxf(fmaxf(s_wmax[n], s_wmax[32 + n]),
                       fmaxf(s_wmax[64 + n], s_wmax[96 + n]));
      float mnew = fmaxf(s_m[n], mw);
      float ps = 0.f;
#pragma unroll
      for (int mt = 0; mt < 2; ++mt) {
        int lb = l_base + wv * 32 + mt * 16 + quad * 4;
        unsigned short u[4];
#pragma unroll
        for (int r = 0; r < 4; ++r) {
          float p = (lb + r < LP_) ? __expf(accs[mt][nt][r] - mnew) : 0.f;
          ps += p;
          u[r] = f2b(p);
        }
        *(ushort4*)&s_P[n * 136 + wv * 32 + mt * 16 + quad * 4] =
            make_ushort4(u[0], u[1], u[2], u[3]);
      }
      ps += __shfl_xor(ps, 16);
      ps += __shfl_xor(ps, 32);
      if (lane < 16) s_wsum[wv * 32 + n] = ps;
    }
    __syncthreads();  // barrier 2
    if (tid < 32) {
      const int n = tid;
      float mw = fmaxf(fmaxf(s_wmax[n], s_wmax[32 + n]),
                       fmaxf(s_wmax[64 + n], s_wmax[96 + n]));
      float mnew = fmaxf(s_m[n], mw);
      float tot = s_wsum[n] + s_wsum[32 + n] + s_wsum[64 + n] + s_wsum[96 + n];
      float rr = __expf(s_m[n] - mnew);
      s_sum[n] = s_sum[n] * rr + tot;
      s_m[n] = mnew;
      s_r[n] = rr;
    }
    __syncthreads();  // barrier 3
    // ---- rescale O, PV: A = P (LDS), B = cT (global/L2) ----
    {
      float rr4[4];
#pragma unroll
      for (int r = 0; r < 4; ++r) rr4[r] = s_r[nt2 * 16 + quad * 4 + r];
#pragma unroll
      for (int ft = 0; ft < 7; ++ft) {
        o[ft][0] *= rr4[0]; o[ft][1] *= rr4[1];
        o[ft][2] *= rr4[2]; o[ft][3] *= rr4[3];
      }
    }
    {
      const unsigned short* crow =
          cTb + (size_t)((fh * 7) * 16 + c16) * 2048 + l_base + quad * 8;
#pragma unroll
      for (int sub = 0; sub < 4; ++sub) {
        bf16x8 ap = *(const bf16x8*)&s_P[(nt2 * 16 + c16) * 136 + sub * 32 + quad * 8];
#pragma unroll
        for (int ft = 0; ft < 7; ++ft) {
          bf16x8 bp8 = *(const bf16x8*)(crow + (size_t)ft * 16 * 2048 + sub * 32);
          o[ft] = MFMA(ap, bp8, o[ft]);
        }
      }
    }
  }

  // ---- epilogue: normalize -> s_AO bf16 (A-layout) ----
  __syncthreads();
  {
    float inv4[4];
#pragma unroll
    for (int r = 0; r < 4; ++r) inv4[r] = 1.f / s_sum[nt2 * 16 + quad * 4 + r];
#pragma unroll
    for (int ft = 0; ft < 7; ++ft) {
      int f = (fh * 7 + ft) * 16 + c16;
#pragma unroll
      for (int r = 0; r < 4; ++r)
        s_AO[(nt2 * 16 + quad * 4 + r) * 232 + f] = f2b(o[ft][r] * inv4[r]);
    }
  }
  __syncthreads();
  // ---- proj: P2[n][feat] = AO[n][f] * WoT[feat][f] ----
  f32x4 pa[2][8];
#pragma unroll
  for (int nt = 0; nt < 2; ++nt)
#pragma unroll
    for (int i = 0; i < 8; ++i) pa[nt][i] = (f32x4){0.f, 0.f, 0.f, 0.f};
#pragma unroll
  for (int ks = 0; ks < 7; ++ks) {
    const int ko = ks * 32 + quad * 8;
    bf16x8 a0 = *(const bf16x8*)&s_AO[c16 * 232 + ko];
    bf16x8 a1 = *(const bf16x8*)&s_AO[(16 + c16) * 232 + ko];
#pragma unroll
    for (int i = 0; i < 8; ++i) {
      int fr = wv * 128 + i * 16 + c16;
      bf16x8 bw = *(const bf16x8*)&WoT[(size_t)fr * 224 + ko];
      pa[0][i] = MFMA(a0, bw, pa[0][i]);
      pa[1][i] = MFMA(a1, bw, pa[1][i]);
    }
  }
  // ---- relu + dot with graph_emb, reduce to logits ----
  float la[2][4];
#pragma unroll
  for (int nt = 0; nt < 2; ++nt)
#pragma unroll
    for (int r = 0; r < 4; ++r) la[nt][r] = 0.f;
  for (int i = 0; i < 8; ++i) {
    int feat = wv * 128 + i * 16 + c16;
    bool fok = feat < FEAT_;
    float bof = fok ? bo[feat] : 0.f;
#pragma unroll
    for (int nt = 0; nt < 2; ++nt) {
#pragma unroll
      for (int r = 0; r < 4; ++r) {
        int ng = n0 + nt * 16 + quad * 4 + r;
        float pv = fmaxf(pa[nt][i][r] + bof, 0.f);
        float gv = (fok && ng < NL_) ? ge[(size_t)ng * 512 + feat] : 0.f;
        la[nt][r] = fmaf(pv, gv, la[nt][r]);
      }
    }
  }
#pragma unroll
  for (int nt = 0; nt < 2; ++nt)
#pragma unroll
    for (int r = 0; r < 4; ++r) {
      float v = la[nt][r];
      v += __shfl_xor(v, 1); v += __shfl_xor(v, 2);
      v += __shfl_xor(v, 4); v += __shfl_xor(v, 8);
      if (c16 == 0) atomicAdd(&s_lg[nt * 16 + quad * 4 + r], v);
    }
  __syncthreads();
  if (tid < 32) {
    int ng = n0 + tid;
    if (ng < NL_) out[(size_t)b * NL_ + ng] = s_lg[tid];
  }
}

// ---------------------------------------------------------------------------
__global__ __launch_bounds__(1024) void k_loss(const float* __restrict__ lgts,
                                               const float* __restrict__ y,
                                               float* __restrict__ loss) {
  __shared__ float red[1024];
  const int tid = threadIdx.x;
  float s = 0.f;
  for (int i = tid; i < B_ * NL_; i += 1024) {
    float l = lgts[i], yy = y[i];
    s += fmaxf(l, 0.f) - l * yy + log1pf(expf(-fabsf(l)));
  }
  red[tid] = s;
  __syncthreads();
  for (int st = 512; st > 0; st >>= 1) {
    if (tid < st) red[tid] += red[tid + st];
    __syncthreads();
  }
  if (tid == 0) loss[0] = red[0] * (1.f / B_);
}

// ---------------------------------------------------------------------------
extern "C" void kernel_launch(void* const* d_in, const int* in_sizes, int n_in,
                              void* d_out, int out_size, void* d_ws, size_t ws_size,
                              hipStream_t stream) {
  const int*   x     = (const int*)  d_in[0];
  const float* y     = (const float*)d_in[1];
  const float* mask  = (const float*)d_in[2];
  const float* we    = (const float*)d_in[3];
  const int*   lidx  = (const int*)  d_in[4];
  const float* lmask = (const float*)d_in[5];
  const float* adj   = (const float*)d_in[6];
  const float* nnb   = (const float*)d_in[7];
  const float* Wg    = (const float*)d_in[8];
  const float* bg    = (const float*)d_in[9];
  const float* Wc    = (const float*)d_in[10];
  const float* bc    = (const float*)d_in[11];
  const float* Wp    = (const float*)d_in[12];
  const float* bp    = (const float*)d_in[13];
  const float* Wo    = (const float*)d_in[14];
  const float* bo    = (const float*)d_in[15];
  float* out = (float*)d_out;
  char* W = (char*)d_ws;

  // ws layout (bytes, all 16-aligned); agg aliases pj+cT (dead before k_cpj)
  unsigned short* pjw  = (unsigned short*)(W + 0);          // 10,485,760
  unsigned short* cT   = (unsigned short*)(W + 10485760);   //  7,340,032
  unsigned short* avgb = (unsigned short*)(W + 17825792);   //  5,713,920
  float*          ge   = (float*)(W + 23539712);            // 18,272,256
  unsigned short* WcT  = (unsigned short*)(W + 41811968);   //  1,638,400
  unsigned short* WpT  = (unsigned short*)(W + 43450368);   //    143,360
  unsigned short* WoT  = (unsigned short*)(W + 43593728);   //    229,376 (end 43,823,104)
  float*          agg  = (float*)(W + 0);

  k_avg<<<(NLP_ * 80 + 255) / 256, 256, 0, stream>>>(we, lidx, lmask, avgb, ge);
  k_agg<<<NL_, 256, 0, stream>>>(adj, ge, nnb, agg);
  k_gh<<<(NL_ + 7) / 8, 256, 0, stream>>>(agg, Wg, bg, ge);
  hipMemsetAsync(cT, 0, 7340032, stream);   // zero pad rows/cols (NaN-safe PV reads)
  k_wct<<<(KW_ * 256 * 320 + 255) / 256, 256, 0, stream>>>(Wc, WcT);
  k_wpt<<<(320 * 224 + 255) / 256, 256, 0, stream>>>(Wp, WpT);
  k_wot<<<(512 * 224 + 255) / 256, 256, 0, stream>>>(Wo, WoT);
  k_cpj<<<dim3(32, B_), 256, 0, stream>>>(x, mask, we, WcT, bc, WpT, bp, cT, pjw);
  k_attn<<<279 * 8, 256, 0, stream>>>(pjw, cT, avgb, WoT, ge, bo, out);
  k_loss<<<1, 1024, 0, stream>>>(out, y, out + B_ * NL_);
}

// Round 4
// 1328.565 us; speedup vs baseline: 4.0370x; 1.1819x over previous
//
#include <hip/hip_runtime.h>
#include <math.h>

#define B_    8
#define L_    2000
#define V_    50000
#define E_    300
#define NL_   8922
#define NLP_  8960   // padded label count (multiple of 64)
#define LW_   10
#define F_    200
#define KW_   10
#define H_    200
#define FEAT_ 500
#define LP_   1991   // L - K + 1

typedef __attribute__((ext_vector_type(8))) short bf16x8;
typedef __attribute__((ext_vector_type(4))) float f32x4;

static __device__ __forceinline__ unsigned short f2b(float f) {
  unsigned u = __builtin_bit_cast(unsigned, f);
  u += 0x7FFF + ((u >> 16) & 1);   // round-to-nearest-even
  return (unsigned short)(u >> 16);
}
static __device__ __forceinline__ float fast_tanh(float x) {
  x = fminf(fmaxf(x, -10.f), 10.f);
  float t = __expf(2.f * x);
  return (t - 1.f) / (t + 1.f);
}

#define MFMA(a, b, c) __builtin_amdgcn_mfma_f32_16x16x32_bf16(a, b, c, 0, 0, 0)

// ---------------------------------------------------------------------------
// label-desc average: ge[n][0..299] fp32, avgb[n][320] bf16 (zero-padded rows/cols)
__global__ __launch_bounds__(256) void k_avg(const float* __restrict__ we,
                                             const int* __restrict__ lidx,
                                             const float* __restrict__ lmask,
                                             unsigned short* __restrict__ avgb,
                                             float* __restrict__ ge) {
  int idx = blockIdx.x * 256 + threadIdx.x;
  if (idx >= NLP_ * 80) return;
  int n = idx / 80, e4 = idx - n * 80;
  if (n >= NL_ || e4 >= 75) {
    *(ushort4*)&avgb[(size_t)n * 320 + e4 * 4] = make_ushort4(0, 0, 0, 0);
    return;
  }
  float ax = 0.f, ay = 0.f, az = 0.f, aw = 0.f, ms = 0.f;
#pragma unroll
  for (int w = 0; w < LW_; ++w) {
    float mw = lmask[n * LW_ + w];
    const float4 f = *(const float4*)&we[(size_t)lidx[n * LW_ + w] * E_ + e4 * 4];
    ax = fmaf(f.x, mw, ax); ay = fmaf(f.y, mw, ay);
    az = fmaf(f.z, mw, az); aw = fmaf(f.w, mw, aw);
    ms += mw;
  }
  float inv = 1.f / ms;
  float4 v = {ax * inv, ay * inv, az * inv, aw * inv};
  *(float4*)&ge[(size_t)n * 512 + e4 * 4] = v;
  *(ushort4*)&avgb[(size_t)n * 320 + e4 * 4] =
      make_ushort4(f2b(v.x), f2b(v.y), f2b(v.z), f2b(v.w));
}

// ---------------------------------------------------------------------------
// agg[n] = (adj[n,:] @ avg) / num_neighbors[n]  (sparse scan; avg read from ge rows)
__global__ __launch_bounds__(256) void k_agg(const float* __restrict__ adj,
                                             const float* __restrict__ ge,
                                             const float* __restrict__ nnb,
                                             float* __restrict__ agg) {
  __shared__ int s_idx[1024];
  __shared__ float s_val[1024];
  __shared__ int s_cnt;
  const int n = blockIdx.x;
  const int tid = threadIdx.x;
  if (tid == 0) s_cnt = 0;
  __syncthreads();
  const float* row = adj + (size_t)n * NL_;
  for (int j = tid; j < NL_; j += 256) {
    float v = row[j];
    if (v != 0.f) {
      int p = atomicAdd(&s_cnt, 1);
      if (p < 1024) { s_idx[p] = j; s_val[p] = v; }
    }
  }
  __syncthreads();
  const int m = min(s_cnt, 1024);
  const float inv = 1.f / nnb[n];
  float a0 = 0.f, a1 = 0.f;
  for (int i = 0; i < m; ++i) {
    const float* ar = ge + (size_t)s_idx[i] * 512;
    float v = s_val[i];
    a0 = fmaf(v, ar[tid], a0);
    if (tid < E_ - 256) a1 = fmaf(v, ar[tid + 256], a1);
  }
  agg[(size_t)n * E_ + tid] = a0 * inv;
  if (tid < E_ - 256) agg[(size_t)n * E_ + tid + 256] = a1 * inv;
}

// ---------------------------------------------------------------------------
// ge[n][300..499] = relu(agg @ Wg + bg); zero-pad ge[n][500..511]
__global__ __launch_bounds__(256) void k_gh(const float* __restrict__ agg,
                                            const float* __restrict__ Wg,
                                            const float* __restrict__ bg,
                                            float* __restrict__ ge) {
  __shared__ float s_agg[2400];  // [e][8]
  const int n0 = blockIdx.x * 8;
  const int tid = threadIdx.x;
  for (int i = tid; i < 2400; i += 256) {
    int e = i >> 3, nn = i & 7;
    int n = n0 + nn;
    s_agg[i] = (n < NL_) ? agg[(size_t)n * E_ + e] : 0.f;
  }
  __syncthreads();
  if (tid < 96) {
    int nn = tid / 12, c = tid - nn * 12;
    int n = n0 + nn;
    if (n < NL_) ge[(size_t)n * 512 + 500 + c] = 0.f;
  }
  if (tid < H_) {
    const int h = tid;
    float bb = bg[h];
    float acc[8];
#pragma unroll
    for (int i = 0; i < 8; ++i) acc[i] = bb;
    for (int e = 0; e < E_; ++e) {
      float w = Wg[(size_t)e * H_ + h];
      float4 a0 = *(const float4*)&s_agg[e * 8];
      float4 a1 = *(const float4*)&s_agg[e * 8 + 4];
      acc[0] = fmaf(a0.x, w, acc[0]); acc[1] = fmaf(a0.y, w, acc[1]);
      acc[2] = fmaf(a0.z, w, acc[2]); acc[3] = fmaf(a0.w, w, acc[3]);
      acc[4] = fmaf(a1.x, w, acc[4]); acc[5] = fmaf(a1.y, w, acc[5]);
      acc[6] = fmaf(a1.z, w, acc[6]); acc[7] = fmaf(a1.w, w, acc[7]);
    }
#pragma unroll
    for (int i = 0; i < 8; ++i) {
      int n = n0 + i;
      if (n < NL_) ge[(size_t)n * 512 + 300 + h] = fmaxf(acc[i], 0.f);
    }
  }
}

// ---------------------------------------------------------------------------
// WcT[k][f(256)][e(320)] = bf16(Wc[f][e][k]), zero pad
__global__ __launch_bounds__(256) void k_wct(const float* __restrict__ Wc,
                                             unsigned short* __restrict__ WcT) {
  int idx = blockIdx.x * 256 + threadIdx.x;
  if (idx >= KW_ * 256 * 320) return;
  int k = idx / (256 * 320);
  int r = idx - k * (256 * 320);
  int f = r / 320, e = r - f * 320;
  float v = (f < F_ && e < E_) ? Wc[((size_t)f * E_ + e) * KW_ + k] : 0.f;
  WcT[idx] = f2b(v);
}

// ---------------------------------------------------------------------------
// WpT[e(320)][f(224)] = bf16(Wp[f][e]), zero pad
__global__ __launch_bounds__(256) void k_wpt(const float* __restrict__ Wp,
                                             unsigned short* __restrict__ WpT) {
  int idx = blockIdx.x * 256 + threadIdx.x;
  if (idx >= 320 * 224) return;
  int e = idx / 224, f = idx - e * 224;
  float v = (e < E_ && f < F_) ? Wp[(size_t)f * E_ + e] : 0.f;
  WpT[idx] = f2b(v);
}

// ---------------------------------------------------------------------------
// WoT[feat(512)][f(224)] = bf16(Wo[f][feat]), zero pad
__global__ __launch_bounds__(256) void k_wot(const float* __restrict__ Wo,
                                             unsigned short* __restrict__ WoT) {
  int idx = blockIdx.x * 256 + threadIdx.x;
  if (idx >= 512 * 224) return;
  int ft = idx / 224, f = idx - ft * 224;
  float v = (ft < FEAT_ && f < F_) ? Wo[(size_t)f * FEAT_ + ft] : 0.f;
  WoT[idx] = f2b(v);
}

// ---------------------------------------------------------------------------
// Fused conv + pj, MFMA bf16. Block = (64 l) x b. 256 blocks.
__global__ __launch_bounds__(256) void k_cpj(const int* __restrict__ x,
                                             const float* __restrict__ mask,
                                             const float* __restrict__ we,
                                             const unsigned short* __restrict__ WcT,
                                             const float* __restrict__ bc,
                                             const unsigned short* __restrict__ WpT,
                                             const float* __restrict__ bp,
                                             unsigned short* __restrict__ cT,
                                             unsigned short* __restrict__ pjo) {
  __shared__ unsigned short s_xe[73 * 328 + 8];  // [row][e(328)] bf16
  __shared__ unsigned short s_cA[64 * 232];      // [l][f(232)] bf16
  const int b = blockIdx.y;
  const int l0 = blockIdx.x * 64;
  const int tid = threadIdx.x;
  const int wv = tid >> 6, lane = tid & 63, quad = lane >> 4, c16 = lane & 15;

  // ---- stage xe (gather + bf16) ----
  for (int i = tid; i < 73 * 75; i += 256) {
    int row = i / 75, e4 = i - row * 75;
    int l = l0 + row;
    float4 v = {0.f, 0.f, 0.f, 0.f};
    if (l < L_) {
      int bl = b * L_ + l;
      v = *(const float4*)&we[(size_t)x[bl] * E_ + e4 * 4];
      float mm = mask[bl];
      v.x *= mm; v.y *= mm; v.z *= mm; v.w *= mm;
    }
    *(ushort4*)&s_xe[row * 328 + e4 * 4] =
        make_ushort4(f2b(v.x), f2b(v.y), f2b(v.z), f2b(v.w));
  }
  for (int i = tid; i < 73 * 7; i += 256) {
    int row = i / 7, c = i - row * 7;
    *(ushort4*)&s_xe[row * 328 + 300 + c * 4] = make_ushort4(0, 0, 0, 0);
  }
  for (int i = tid; i < 64 * 8; i += 256) {
    int row = i >> 3, c = i & 7;
    *(ushort4*)&s_cA[row * 232 + 200 + c * 4] = make_ushort4(0, 0, 0, 0);
  }
  __syncthreads();

  // ---- conv GEMM: 4 m-tiles x 4 f-tiles per wave ----
  f32x4 acc[4][4];
#pragma unroll
  for (int mt = 0; mt < 4; ++mt)
#pragma unroll
    for (int j = 0; j < 4; ++j) acc[mt][j] = (f32x4){0.f, 0.f, 0.f, 0.f};
  for (int koff = 0; koff < KW_; ++koff) {
#pragma unroll
    for (int ks = 0; ks < 10; ++ks) {
      bf16x8 a[4];
#pragma unroll
      for (int mt = 0; mt < 4; ++mt)
        a[mt] = *(const bf16x8*)&s_xe[(mt * 16 + c16 + koff) * 328 + ks * 32 + quad * 8];
#pragma unroll
      for (int j = 0; j < 4; ++j) {
        int f = (wv * 4 + j) * 16 + c16;
        bf16x8 bw = *(const bf16x8*)&WcT[((size_t)koff * 256 + f) * 320 + ks * 32 + quad * 8];
#pragma unroll
        for (int mt = 0; mt < 4; ++mt) acc[mt][j] = MFMA(a[mt], bw, acc[mt][j]);
      }
    }
  }
  // ---- conv epilogue: bias+relu, write s_cA + cT ----
#pragma unroll
  for (int j = 0; j < 4; ++j) {
    int f = (wv * 4 + j) * 16 + c16;
    if (f < F_) {
      float bcv = bc[f];
#pragma unroll
      for (int mt = 0; mt < 4; ++mt) {
        unsigned short u[4];
#pragma unroll
        for (int r = 0; r < 4; ++r) u[r] = f2b(fmaxf(acc[mt][j][r] + bcv, 0.f));
        int ll = mt * 16 + quad * 4;
#pragma unroll
        for (int r = 0; r < 4; ++r) s_cA[(ll + r) * 232 + f] = u[r];
        int lg = l0 + ll;
        unsigned short* dst = &cT[((size_t)b * 224 + f) * 2048 + lg];
        if (lg + 3 < LP_) {
          *(ushort4*)dst = make_ushort4(u[0], u[1], u[2], u[3]);
        } else {
#pragma unroll
          for (int r = 0; r < 4; ++r)
            if (lg + r < LP_) dst[r] = u[r];
        }
      }
    }
  }
  __syncthreads();

  // ---- pj GEMM: 4 m-tiles x 5 e-tiles per wave, K = 224 ----
  f32x4 pacc[4][5];
#pragma unroll
  for (int mt = 0; mt < 4; ++mt)
#pragma unroll
    for (int j = 0; j < 5; ++j) pacc[mt][j] = (f32x4){0.f, 0.f, 0.f, 0.f};
#pragma unroll
  for (int ks = 0; ks < 7; ++ks) {
    bf16x8 a[4];
#pragma unroll
    for (int mt = 0; mt < 4; ++mt)
      a[mt] = *(const bf16x8*)&s_cA[(mt * 16 + c16) * 232 + ks * 32 + quad * 8];
#pragma unroll
    for (int j = 0; j < 5; ++j) {
      int e = (wv * 5 + j) * 16 + c16;
      bf16x8 bw = *(const bf16x8*)&WpT[(size_t)e * 224 + ks * 32 + quad * 8];
#pragma unroll
      for (int mt = 0; mt < 4; ++mt) pacc[mt][j] = MFMA(a[mt], bw, pacc[mt][j]);
    }
  }
  // ---- pj epilogue: fast tanh, transpose via LDS (reuse s_xe), store ----
  unsigned short* s_po = s_xe;
#pragma unroll
  for (int j = 0; j < 5; ++j) {
    int e = (wv * 5 + j) * 16 + c16;
    if (e < E_) {
      float bpe = bp[e];
#pragma unroll
      for (int mt = 0; mt < 4; ++mt)
#pragma unroll
        for (int r = 0; r < 4; ++r)
          s_po[(mt * 16 + quad * 4 + r) * 328 + e] = f2b(fast_tanh(pacc[mt][j][r] + bpe));
    }
  }
  __syncthreads();
  for (int i = tid; i < 64 * 80; i += 256) {
    int row = i / 80, c4 = i - row * 80;
    ushort4 u = make_ushort4(0, 0, 0, 0);
    if (c4 < 75) u = *(const ushort4*)&s_po[row * 328 + c4 * 4];
    *(ushort4*)&pjo[((size_t)b * 2048 + l0 + row) * 320 + c4 * 4] = u;
  }
}

// ---------------------------------------------------------------------------
// Fused attention + proj + logits, 64 labels/block, no-max softmax, 2 barriers/lc.
__global__ __launch_bounds__(256, 2) void k_attn(
    const unsigned short* __restrict__ pj,    // [8][2048][320]
    const unsigned short* __restrict__ cT,    // [8][224][2048]
    const unsigned short* __restrict__ avgb,  // [8960][320]
    const unsigned short* __restrict__ WoT,   // [512][224]
    const float* __restrict__ ge,             // [NL][512]
    const float* __restrict__ bo,
    float* __restrict__ out) {
  __shared__ __attribute__((aligned(16))) unsigned char smem[60928];
  unsigned short* s_avg = (unsigned short*)smem;            // [64][328] 41,984 B (scores phase)
  unsigned short* s_AO  = (unsigned short*)smem;            // [64][232] alias (epilogue)
  unsigned short* s_P   = (unsigned short*)(smem + 41984);  // [64][136] 17,408 B
  float* s_wsum = (float*)(smem + 59392);  // [4][64]
  float* s_sum  = (float*)(smem + 60416);  // [64]
  float* s_lg   = (float*)(smem + 60672);  // [64]

  const int tid = threadIdx.x;
  const int b  = blockIdx.x & 7;           // XCD-locality swizzle
  const int n0 = (blockIdx.x >> 3) << 6;   // 64 labels per block
  const int wv = tid >> 6, lane = tid & 63, quad = lane >> 4, c16 = lane & 15;
  const int ntp = wv >> 1, fh = wv & 1;    // PV: n-tile pair, f-half

  if (tid < 64) s_lg[tid] = 0.f;
  // stage avg tile [64][328] (16B chunks)
  for (int i = tid; i < 64 * 40; i += 256) {
    int n = i / 40, c8 = i - n * 40;
    *(uint4*)&s_avg[n * 328 + c8 * 8] =
        *(const uint4*)&avgb[(size_t)(n0 + n) * 320 + c8 * 8];
  }
  __syncthreads();

  const unsigned short* pjb = pj + (size_t)b * (2048 * 320);
  const unsigned short* cTb = cT + (size_t)b * (224 * 2048);

  f32x4 o[2][7];
#pragma unroll
  for (int i = 0; i < 2; ++i)
#pragma unroll
    for (int j = 0; j < 7; ++j) o[i][j] = (f32x4){0.f, 0.f, 0.f, 0.f};
  float ssum[4] = {0.f, 0.f, 0.f, 0.f};

  for (int lc = 0; lc < 16; ++lc) {
    const int l_base = lc << 7;
    // ---- scores: A = pj rows (global/L2), B = s_avg (LDS) ----
    f32x4 accs[2][4];
#pragma unroll
    for (int mt = 0; mt < 2; ++mt)
#pragma unroll
      for (int nt = 0; nt < 4; ++nt) accs[mt][nt] = (f32x4){0.f, 0.f, 0.f, 0.f};
    {
      const unsigned short* pr0 =
          pjb + (size_t)(l_base + wv * 32 + c16) * 320 + quad * 8;
#pragma unroll
      for (int ks = 0; ks < 10; ++ks) {
        bf16x8 a0 = *(const bf16x8*)(pr0 + ks * 32);
        bf16x8 a1 = *(const bf16x8*)(pr0 + 16 * 320 + ks * 32);
#pragma unroll
        for (int nt = 0; nt < 4; ++nt) {
          bf16x8 bb = *(const bf16x8*)&s_avg[(nt * 16 + c16) * 328 + ks * 32 + quad * 8];
          accs[0][nt] = MFMA(a0, bb, accs[0][nt]);
          accs[1][nt] = MFMA(a1, bb, accs[1][nt]);
        }
      }
    }
    __syncthreads();  // barrier 1: prev PV done reading s_P
    // ---- exp (no max needed: |S| bounded), P write, register sums ----
#pragma unroll
    for (int nt = 0; nt < 4; ++nt) {
      float psum = 0.f;
#pragma unroll
      for (int mt = 0; mt < 2; ++mt) {
        const int lb = l_base + wv * 32 + mt * 16 + quad * 4;
        unsigned short u[4];
#pragma unroll
        for (int r = 0; r < 4; ++r) {
          float p = (lb + r < LP_) ? __expf(accs[mt][nt][r]) : 0.f;
          psum += p;
          u[r] = f2b(p);
        }
        *(ushort4*)&s_P[(nt * 16 + c16) * 136 + wv * 32 + mt * 16 + quad * 4] =
            make_ushort4(u[0], u[1], u[2], u[3]);
      }
      psum += __shfl_xor(psum, 16);
      psum += __shfl_xor(psum, 32);
      ssum[nt] += psum;
    }
    __syncthreads();  // barrier 2: P visible
    // ---- PV: A = P (LDS), B = cT rows (global/L2) ----
    {
      const unsigned short* crow =
          cTb + (size_t)(fh * 112 + c16) * 2048 + l_base + quad * 8;
#pragma unroll
      for (int sub = 0; sub < 4; ++sub) {
        bf16x8 ap0 = *(const bf16x8*)&s_P[((ntp * 2) * 16 + c16) * 136 + sub * 32 + quad * 8];
        bf16x8 ap1 = *(const bf16x8*)&s_P[((ntp * 2 + 1) * 16 + c16) * 136 + sub * 32 + quad * 8];
#pragma unroll
        for (int ft = 0; ft < 7; ++ft) {
          bf16x8 bp8 = *(const bf16x8*)(crow + (size_t)ft * 16 * 2048 + sub * 32);
          o[0][ft] = MFMA(ap0, bp8, o[0][ft]);
          o[1][ft] = MFMA(ap1, bp8, o[1][ft]);
        }
      }
    }
  }

  // ---- final sums ----
  if (lane < 16) {
#pragma unroll
    for (int nt = 0; nt < 4; ++nt) s_wsum[wv * 64 + nt * 16 + lane] = ssum[nt];
  }
  __syncthreads();
  if (tid < 64)
    s_sum[tid] = s_wsum[tid] + s_wsum[64 + tid] + s_wsum[128 + tid] + s_wsum[192 + tid];
  __syncthreads();
  // ---- normalize -> s_AO bf16 (A-layout), aliases s_avg (dead) ----
#pragma unroll
  for (int nt2 = 0; nt2 < 2; ++nt2) {
    const int nb = (ntp * 2 + nt2) * 16 + quad * 4;
    float inv4[4];
#pragma unroll
    for (int r = 0; r < 4; ++r) inv4[r] = 1.f / s_sum[nb + r];
#pragma unroll
    for (int ft = 0; ft < 7; ++ft) {
      int f = fh * 112 + ft * 16 + c16;
#pragma unroll
      for (int r = 0; r < 4; ++r)
        s_AO[(nb + r) * 232 + f] = f2b(o[nt2][ft][r] * inv4[r]);
    }
  }
  __syncthreads();
  // ---- proj: 64 n x 512 feat; wave owns feat quarter wv*128 ----
  f32x4 pa[4][8];
#pragma unroll
  for (int mt = 0; mt < 4; ++mt)
#pragma unroll
    for (int nt = 0; nt < 8; ++nt) pa[mt][nt] = (f32x4){0.f, 0.f, 0.f, 0.f};
#pragma unroll
  for (int ks = 0; ks < 7; ++ks) {
    bf16x8 a[4];
#pragma unroll
    for (int mt = 0; mt < 4; ++mt)
      a[mt] = *(const bf16x8*)&s_AO[(mt * 16 + c16) * 232 + ks * 32 + quad * 8];
#pragma unroll
    for (int nt = 0; nt < 8; ++nt) {
      int fr = wv * 128 + nt * 16 + c16;
      bf16x8 bw = *(const bf16x8*)&WoT[(size_t)fr * 224 + ks * 32 + quad * 8];
#pragma unroll
      for (int mt = 0; mt < 4; ++mt) pa[mt][nt] = MFMA(a[mt], bw, pa[mt][nt]);
    }
  }
  // ---- relu + dot graph_emb -> logits ----
  float la[4][4];
#pragma unroll
  for (int mt = 0; mt < 4; ++mt)
#pragma unroll
    for (int r = 0; r < 4; ++r) la[mt][r] = 0.f;
#pragma unroll
  for (int nt = 0; nt < 8; ++nt) {
    int feat = wv * 128 + nt * 16 + c16;
    bool fok = feat < FEAT_;
    float bof = fok ? bo[feat] : 0.f;
#pragma unroll
    for (int mt = 0; mt < 4; ++mt) {
#pragma unroll
      for (int r = 0; r < 4; ++r) {
        int ng = n0 + mt * 16 + quad * 4 + r;
        float pv = fmaxf(pa[mt][nt][r] + bof, 0.f);
        float gv = (fok && ng < NL_) ? ge[(size_t)ng * 512 + feat] : 0.f;
        la[mt][r] = fmaf(pv, gv, la[mt][r]);
      }
    }
  }
#pragma unroll
  for (int mt = 0; mt < 4; ++mt)
#pragma unroll
    for (int r = 0; r < 4; ++r) {
      float v = la[mt][r];
      v += __shfl_xor(v, 1); v += __shfl_xor(v, 2);
      v += __shfl_xor(v, 4); v += __shfl_xor(v, 8);
      if (c16 == 0) atomicAdd(&s_lg[mt * 16 + quad * 4 + r], v);
    }
  __syncthreads();
  if (tid < 64) {
    int ng = n0 + tid;
    if (ng < NL_) out[(size_t)b * NL_ + ng] = s_lg[tid];
  }
}

// ---------------------------------------------------------------------------
__global__ __launch_bounds__(1024) void k_loss(const float* __restrict__ lgts,
                                               const float* __restrict__ y,
                                               float* __restrict__ loss) {
  __shared__ float red[1024];
  const int tid = threadIdx.x;
  float s = 0.f;
  for (int i = tid; i < B_ * NL_; i += 1024) {
    float l = lgts[i], yy = y[i];
    s += fmaxf(l, 0.f) - l * yy + log1pf(expf(-fabsf(l)));
  }
  red[tid] = s;
  __syncthreads();
  for (int st = 512; st > 0; st >>= 1) {
    if (tid < st) red[tid] += red[tid + st];
    __syncthreads();
  }
  if (tid == 0) loss[0] = red[0] * (1.f / B_);
}

// ---------------------------------------------------------------------------
extern "C" void kernel_launch(void* const* d_in, const int* in_sizes, int n_in,
                              void* d_out, int out_size, void* d_ws, size_t ws_size,
                              hipStream_t stream) {
  const int*   x     = (const int*)  d_in[0];
  const float* y     = (const float*)d_in[1];
  const float* mask  = (const float*)d_in[2];
  const float* we    = (const float*)d_in[3];
  const int*   lidx  = (const int*)  d_in[4];
  const float* lmask = (const float*)d_in[5];
  const float* adj   = (const float*)d_in[6];
  const float* nnb   = (const float*)d_in[7];
  const float* Wg    = (const float*)d_in[8];
  const float* bg    = (const float*)d_in[9];
  const float* Wc    = (const float*)d_in[10];
  const float* bc    = (const float*)d_in[11];
  const float* Wp    = (const float*)d_in[12];
  const float* bp    = (const float*)d_in[13];
  const float* Wo    = (const float*)d_in[14];
  const float* bo    = (const float*)d_in[15];
  float* out = (float*)d_out;
  char* W = (char*)d_ws;

  // ws layout (bytes, 16-aligned); agg aliases pj+cT region (dead before k_cpj)
  unsigned short* pjw  = (unsigned short*)(W + 0);          // 10,485,760
  unsigned short* cT   = (unsigned short*)(W + 10485760);   //  7,340,032
  unsigned short* avgb = (unsigned short*)(W + 17825792);   //  5,734,400
  float*          ge   = (float*)(W + 23560192);            // 18,350,080
  unsigned short* WcT  = (unsigned short*)(W + 41910272);   //  1,638,400
  unsigned short* WpT  = (unsigned short*)(W + 43548672);   //    143,360
  unsigned short* WoT  = (unsigned short*)(W + 43692032);   //    229,376 (end 43,921,408)
  float*          agg  = (float*)(W + 0);

  k_avg<<<(NLP_ * 80 + 255) / 256, 256, 0, stream>>>(we, lidx, lmask, avgb, ge);
  k_agg<<<NL_, 256, 0, stream>>>(adj, ge, nnb, agg);
  k_gh<<<(NL_ + 7) / 8, 256, 0, stream>>>(agg, Wg, bg, ge);
  hipMemsetAsync(cT, 0, 7340032, stream);   // zero pad rows/cols (NaN-safe PV reads)
  k_wct<<<(KW_ * 256 * 320 + 255) / 256, 256, 0, stream>>>(Wc, WcT);
  k_wpt<<<(320 * 224 + 255) / 256, 256, 0, stream>>>(Wp, WpT);
  k_wot<<<(512 * 224 + 255) / 256, 256, 0, stream>>>(Wo, WoT);
  k_cpj<<<dim3(32, B_), 256, 0, stream>>>(x, mask, we, WcT, bc, WpT, bp, cT, pjw);
  k_attn<<<140 * 8, 256, 0, stream>>>(pjw, cT, avgb, WoT, ge, bo, out);
  k_loss<<<1, 1024, 0, stream>>>(out, y, out + B_ * NL_);
}

// Round 5
// 1237.224 us; speedup vs baseline: 4.3351x; 1.0738x over previous
//
#include <hip/hip_runtime.h>
#include <math.h>

#define B_    8
#define L_    2000
#define V_    50000
#define E_    300
#define NL_   8922
#define NLP_  8960   // padded label count (multiple of 64)
#define LW_   10
#define F_    200
#define KW_   10
#define H_    200
#define FEAT_ 500
#define LP_   1991   // L - K + 1

typedef __attribute__((ext_vector_type(8))) short bf16x8;
typedef __attribute__((ext_vector_type(4))) float f32x4;

static __device__ __forceinline__ unsigned short f2b(float f) {
  unsigned u = __builtin_bit_cast(unsigned, f);
  u += 0x7FFF + ((u >> 16) & 1);   // round-to-nearest-even
  return (unsigned short)(u >> 16);
}
static __device__ __forceinline__ float b2f(unsigned short u) {
  unsigned v = ((unsigned)u) << 16;
  return __builtin_bit_cast(float, v);
}
static __device__ __forceinline__ float fast_tanh(float x) {
  x = fminf(fmaxf(x, -10.f), 10.f);
  float t = __expf(2.f * x);
  return (t - 1.f) / (t + 1.f);
}

#define MFMA(a, b, c) __builtin_amdgcn_mfma_f32_16x16x32_bf16(a, b, c, 0, 0, 0)

// Fragment conventions (mfma_f32_16x16x32_bf16, m89/m91-verified):
//   A[m][k]: m = lane&15, k = (lane>>4)*8 + j
//   B[n][k]: n = lane&15, k = (lane>>4)*8 + j
//   D[m][n]: m-row = (lane>>4)*4 + reg, n-col = lane&15
// Frag-major layout: tile*512 + lane*8 + j  -> wave load = 1 KB contiguous.

// ---------------------------------------------------------------------------
__global__ __launch_bounds__(256) void k_avg(const float* __restrict__ we,
                                             const int* __restrict__ lidx,
                                             const float* __restrict__ lmask,
                                             float* __restrict__ avg,
                                             unsigned short* __restrict__ avgb,
                                             unsigned short* __restrict__ geb) {
  int idx = blockIdx.x * 256 + threadIdx.x;
  if (idx >= NLP_ * 80) return;
  int n = idx / 80, e4 = idx - n * 80;
  if (n >= NL_ || e4 >= 75) {
    *(ushort4*)&avgb[(size_t)n * 320 + e4 * 4] = make_ushort4(0, 0, 0, 0);
    return;
  }
  float ax = 0.f, ay = 0.f, az = 0.f, aw = 0.f, ms = 0.f;
#pragma unroll
  for (int w = 0; w < LW_; ++w) {
    float mw = lmask[n * LW_ + w];
    const float4 f = *(const float4*)&we[(size_t)lidx[n * LW_ + w] * E_ + e4 * 4];
    ax = fmaf(f.x, mw, ax); ay = fmaf(f.y, mw, ay);
    az = fmaf(f.z, mw, az); aw = fmaf(f.w, mw, aw);
    ms += mw;
  }
  float inv = 1.f / ms;
  float4 v = {ax * inv, ay * inv, az * inv, aw * inv};
  *(float4*)&avg[(size_t)n * 300 + e4 * 4] = v;
  ushort4 ub = make_ushort4(f2b(v.x), f2b(v.y), f2b(v.z), f2b(v.w));
  *(ushort4*)&avgb[(size_t)n * 320 + e4 * 4] = ub;
  *(ushort4*)&geb[(size_t)n * 512 + e4 * 4] = ub;
}

// ---------------------------------------------------------------------------
__global__ __launch_bounds__(256) void k_agg(const float* __restrict__ adj,
                                             const float* __restrict__ avg,
                                             const float* __restrict__ nnb,
                                             float* __restrict__ agg) {
  __shared__ int s_idx[1024];
  __shared__ float s_val[1024];
  __shared__ int s_cnt;
  const int n = blockIdx.x;
  const int tid = threadIdx.x;
  if (tid == 0) s_cnt = 0;
  __syncthreads();
  const float* row = adj + (size_t)n * NL_;
  for (int j = tid; j < NL_; j += 256) {
    float v = row[j];
    if (v != 0.f) {
      int p = atomicAdd(&s_cnt, 1);
      if (p < 1024) { s_idx[p] = j; s_val[p] = v; }
    }
  }
  __syncthreads();
  const int m = min(s_cnt, 1024);
  const float inv = 1.f / nnb[n];
  float a0 = 0.f, a1 = 0.f;
  for (int i = 0; i < m; ++i) {
    const float* ar = avg + (size_t)s_idx[i] * 300;
    float v = s_val[i];
    a0 = fmaf(v, ar[tid], a0);
    if (tid < E_ - 256) a1 = fmaf(v, ar[tid + 256], a1);
  }
  agg[(size_t)n * E_ + tid] = a0 * inv;
  if (tid < E_ - 256) agg[(size_t)n * E_ + tid + 256] = a1 * inv;
}

// ---------------------------------------------------------------------------
__global__ __launch_bounds__(256) void k_gh(const float* __restrict__ agg,
                                            const float* __restrict__ Wg,
                                            const float* __restrict__ bg,
                                            unsigned short* __restrict__ geb) {
  __shared__ float s_agg[2400];  // [e][8]
  const int n0 = blockIdx.x * 8;
  const int tid = threadIdx.x;
  for (int i = tid; i < 2400; i += 256) {
    int e = i >> 3, nn = i & 7;
    int n = n0 + nn;
    s_agg[i] = (n < NL_) ? agg[(size_t)n * E_ + e] : 0.f;
  }
  __syncthreads();
  if (tid < 96) {
    int nn = tid / 12, c = tid - nn * 12;
    int n = n0 + nn;
    if (n < NL_) geb[(size_t)n * 512 + 500 + c] = 0;
  }
  if (tid < H_) {
    const int h = tid;
    float bb = bg[h];
    float acc[8];
#pragma unroll
    for (int i = 0; i < 8; ++i) acc[i] = bb;
    for (int e = 0; e < E_; ++e) {
      float w = Wg[(size_t)e * H_ + h];
      float4 a0 = *(const float4*)&s_agg[e * 8];
      float4 a1 = *(const float4*)&s_agg[e * 8 + 4];
      acc[0] = fmaf(a0.x, w, acc[0]); acc[1] = fmaf(a0.y, w, acc[1]);
      acc[2] = fmaf(a0.z, w, acc[2]); acc[3] = fmaf(a0.w, w, acc[3]);
      acc[4] = fmaf(a1.x, w, acc[4]); acc[5] = fmaf(a1.y, w, acc[5]);
      acc[6] = fmaf(a1.z, w, acc[6]); acc[7] = fmaf(a1.w, w, acc[7]);
    }
#pragma unroll
    for (int i = 0; i < 8; ++i) {
      int n = n0 + i;
      if (n < NL_) geb[(size_t)n * 512 + 300 + h] = f2b(fmaxf(acc[i], 0.f));
    }
  }
}

// ---------------------------------------------------------------------------
// WcF frag-major: [koff(10)][ft(16)][ks(10)][512]
__global__ __launch_bounds__(256) void k_wct(const float* __restrict__ Wc,
                                             unsigned short* __restrict__ WcF) {
  int idx = blockIdx.x * 256 + threadIdx.x;
  if (idx >= KW_ * 16 * 10 * 512) return;
  int koff = idx / (16 * 10 * 512);
  int rem = idx - koff * (16 * 10 * 512);
  int ft = rem / (10 * 512);
  int rem2 = rem - ft * (10 * 512);
  int ks = rem2 >> 9;
  int t = rem2 & 511;
  int lane = t >> 3, j = t & 7;
  int f = ft * 16 + (lane & 15);
  int e = ks * 32 + (lane >> 4) * 8 + j;
  float v = (f < F_ && e < E_) ? Wc[((size_t)f * E_ + e) * KW_ + koff] : 0.f;
  WcF[idx] = f2b(v);
}

// ---------------------------------------------------------------------------
// WpF frag-major: [et(20)][kt(7)][512]
__global__ __launch_bounds__(256) void k_wpt(const float* __restrict__ Wp,
                                             unsigned short* __restrict__ WpF) {
  int idx = blockIdx.x * 256 + threadIdx.x;
  if (idx >= 20 * 7 * 512) return;
  int et = idx / (7 * 512);
  int rem = idx - et * (7 * 512);
  int kt = rem >> 9;
  int t = rem & 511;
  int lane = t >> 3, j = t & 7;
  int e = et * 16 + (lane & 15);
  int f = kt * 32 + (lane >> 4) * 8 + j;
  float v = (e < E_ && f < F_) ? Wp[(size_t)f * E_ + e] : 0.f;
  WpF[idx] = f2b(v);
}

// ---------------------------------------------------------------------------
// WoF frag-major: [g(32)][kt(7)][512]
__global__ __launch_bounds__(256) void k_wot(const float* __restrict__ Wo,
                                             unsigned short* __restrict__ WoF) {
  int idx = blockIdx.x * 256 + threadIdx.x;
  if (idx >= 32 * 7 * 512) return;
  int g = idx / (7 * 512);
  int rem = idx - g * (7 * 512);
  int kt = rem >> 9;
  int t = rem & 511;
  int lane = t >> 3, j = t & 7;
  int feat = (g >> 3) * 128 + (g & 7) * 16 + (lane & 15);
  int f = kt * 32 + (lane >> 4) * 8 + j;
  float v = (feat < FEAT_ && f < F_) ? Wo[(size_t)f * FEAT_ + feat] : 0.f;
  WoF[idx] = f2b(v);
}

// ---------------------------------------------------------------------------
// Fused conv + pj -> cF [b][ft2(16)][su(64)][512], pjF [b][lt(128)][ks(10)][512]
__global__ __launch_bounds__(256) void k_cpj(const int* __restrict__ x,
                                             const float* __restrict__ mask,
                                             const float* __restrict__ we,
                                             const unsigned short* __restrict__ WcF,
                                             const float* __restrict__ bc,
                                             const unsigned short* __restrict__ WpF,
                                             const float* __restrict__ bp,
                                             unsigned short* __restrict__ cF,
                                             unsigned short* __restrict__ pjF) {
  __shared__ __attribute__((aligned(16))) unsigned char smem[78896];
  unsigned short* s_xe  = (unsigned short*)smem;            // [73][344] 50224 B
  unsigned short* s_pjF = (unsigned short*)smem;            // [4][10][512] alias
  unsigned short* s_cA  = (unsigned short*)(smem + 50224);  // [4][7][512] 28672 B

  const int b = blockIdx.y;
  const int l0 = blockIdx.x * 64;
  const int tid = threadIdx.x;
  const int wv = tid >> 6, lane = tid & 63, quad = lane >> 4, c16 = lane & 15;

  // ---- stage xe (gather + bf16) ----
  for (int i = tid; i < 73 * 75; i += 256) {
    int row = i / 75, e4 = i - row * 75;
    int l = l0 + row;
    float4 v = {0.f, 0.f, 0.f, 0.f};
    if (l < L_) {
      int bl = b * L_ + l;
      v = *(const float4*)&we[(size_t)x[bl] * E_ + e4 * 4];
      float mm = mask[bl];
      v.x *= mm; v.y *= mm; v.z *= mm; v.w *= mm;
    }
    *(ushort4*)&s_xe[row * 344 + e4 * 4] =
        make_ushort4(f2b(v.x), f2b(v.y), f2b(v.z), f2b(v.w));
  }
  for (int i = tid; i < 73 * 5; i += 256) {   // zero e 300..319
    int row = i / 5, c = i - row * 5;
    *(ushort4*)&s_xe[row * 344 + (75 + c) * 4] = make_ushort4(0, 0, 0, 0);
  }
  __syncthreads();

  // ---- conv GEMM ----
  f32x4 acc[4][4];
#pragma unroll
  for (int mt = 0; mt < 4; ++mt)
#pragma unroll
    for (int j = 0; j < 4; ++j) acc[mt][j] = (f32x4){0.f, 0.f, 0.f, 0.f};
  for (int koff = 0; koff < KW_; ++koff) {
#pragma unroll
    for (int ks = 0; ks < 10; ++ks) {
      bf16x8 a[4];
#pragma unroll
      for (int mt = 0; mt < 4; ++mt)
        a[mt] = *(const bf16x8*)&s_xe[(mt * 16 + c16 + koff) * 344 + ks * 32 + quad * 8];
#pragma unroll
      for (int jj = 0; jj < 4; ++jj) {
        bf16x8 bw = *(const bf16x8*)
            &WcF[(((size_t)((koff * 16 + wv * 4 + jj) * 10 + ks)) << 9) + (lane << 3)];
#pragma unroll
        for (int mt = 0; mt < 4; ++mt) acc[mt][jj] = MFMA(a[mt], bw, acc[mt][jj]);
      }
    }
  }
  // ---- conv epilogue: bias+relu -> cF (B-frag global) + s_cA (A-frag LDS) ----
  unsigned short* cFb = cF + (size_t)b * (16 * 64 * 512);
#pragma unroll
  for (int jj = 0; jj < 4; ++jj) {
    const int ft2 = wv * 4 + jj;
    const int f = ft2 * 16 + c16;
    const float bcv = (f < F_) ? bc[f] : 0.f;
    const int kt = ft2 >> 1;
    const int qA = ((ft2 & 1) << 1) | (c16 >> 3);
    const int jA = c16 & 7;
#pragma unroll
    for (int mt = 0; mt < 4; ++mt) {
      unsigned short u[4];
#pragma unroll
      for (int r = 0; r < 4; ++r) u[r] = f2b(fmaxf(acc[mt][jj][r] + bcv, 0.f));
      int su = (l0 >> 5) + (mt >> 1);
      int lane_c = ((((mt & 1) << 1) | (quad >> 1)) << 4) + c16;
      *(ushort4*)&cFb[(((size_t)(ft2 * 64 + su)) << 9) + lane_c * 8 + ((quad & 1) << 2)] =
          make_ushort4(u[0], u[1], u[2], u[3]);
      if (ft2 < 14) {
#pragma unroll
        for (int r = 0; r < 4; ++r)
          s_cA[(((size_t)(mt * 7 + kt)) << 9) + ((qA << 4) + quad * 4 + r) * 8 + jA] = u[r];
      }
    }
  }
  __syncthreads();

  // ---- pj GEMM: K = 224 ----
  f32x4 pacc[4][5];
#pragma unroll
  for (int mt = 0; mt < 4; ++mt)
#pragma unroll
    for (int j = 0; j < 5; ++j) pacc[mt][j] = (f32x4){0.f, 0.f, 0.f, 0.f};
#pragma unroll
  for (int kt = 0; kt < 7; ++kt) {
    bf16x8 a[4];
#pragma unroll
    for (int mt = 0; mt < 4; ++mt)
      a[mt] = *(const bf16x8*)&s_cA[(((size_t)(mt * 7 + kt)) << 9) + (lane << 3)];
#pragma unroll
    for (int j = 0; j < 5; ++j) {
      bf16x8 bw = *(const bf16x8*)
          &WpF[(((size_t)((wv * 5 + j) * 7 + kt)) << 9) + (lane << 3)];
#pragma unroll
      for (int mt = 0; mt < 4; ++mt) pacc[mt][j] = MFMA(a[mt], bw, pacc[mt][j]);
    }
  }
  __syncthreads();  // s_xe dead -> s_pjF alias safe
  // ---- pj epilogue: tanh -> s_pjF frag-major ----
#pragma unroll
  for (int j = 0; j < 5; ++j) {
    const int et = wv * 5 + j;
    const int e = et * 16 + c16;
    const float bpe = (e < E_) ? bp[e] : 0.f;
    const int ks = et >> 1;
    const int qP = ((et & 1) << 1) | (c16 >> 3);
    const int jP = c16 & 7;
#pragma unroll
    for (int mt = 0; mt < 4; ++mt) {
#pragma unroll
      for (int r = 0; r < 4; ++r) {
        float v = (e < E_) ? fast_tanh(pacc[mt][j][r] + bpe) : 0.f;
        s_pjF[(((size_t)(mt * 10 + ks)) << 9) + ((qP << 4) + quad * 4 + r) * 8 + jP] = f2b(v);
      }
    }
  }
  __syncthreads();
  // ---- contiguous copy-out (20480 shorts) ----
  {
    unsigned short* dst = pjF + (((size_t)((b * 128 + (l0 >> 4)) * 10)) << 9);
    for (int i = tid; i < 2560; i += 256)
      *(uint4*)&dst[i * 8] = *(const uint4*)&s_pjF[i * 8];
  }
}

// ---------------------------------------------------------------------------
// Fused attention + proj + logits, 64 labels/block, frag-major operands.
__global__ __launch_bounds__(256, 2) void k_attn(
    const unsigned short* __restrict__ pjF,   // [8][128][10][512]
    const unsigned short* __restrict__ cF,    // [8][16][64][512]
    const unsigned short* __restrict__ avgb,  // [8960][320]
    const unsigned short* __restrict__ WoF,   // [32][7][512]
    const unsigned short* __restrict__ geb,   // [8960][512]
    const float* __restrict__ bo,
    float* __restrict__ out) {
  __shared__ __attribute__((aligned(16))) unsigned char smem[58880];
  unsigned short* s_avgF = (unsigned short*)smem;            // [40][512] 40960 B
  unsigned short* s_AOF  = (unsigned short*)smem;            // [28][512] alias
  unsigned short* s_PF   = (unsigned short*)(smem + 40960);  // [16][512] 16384 B
  float* s_wsum = (float*)(smem + 57344);
  float* s_sum  = (float*)(smem + 58368);
  float* s_lg   = (float*)(smem + 58624);

  const int tid = threadIdx.x;
  const int b  = blockIdx.x & 7;
  const int n0 = (blockIdx.x >> 3) << 6;
  const int wv = tid >> 6, lane = tid & 63, quad = lane >> 4, c16 = lane & 15;

  if (tid < 64) s_lg[tid] = 0.f;
  for (int i = tid; i < 2560; i += 256) {   // stage avg frag-major
    int nl = i / 40, eo = i - nl * 40;
    int lane_s = ((eo & 3) << 4) | (nl & 15);
    *(uint4*)&s_avgF[(((size_t)((eo >> 2) * 4 + (nl >> 4))) << 9) + lane_s * 8] =
        *(const uint4*)&avgb[(size_t)(n0 + nl) * 320 + eo * 8];
  }
  __syncthreads();

  const unsigned short* pjb = pjF + (size_t)b * (128 * 10 * 512);
  const unsigned short* cFb = cF + (size_t)b * (16 * 64 * 512);

  f32x4 o[4][4];
#pragma unroll
  for (int i = 0; i < 4; ++i)
#pragma unroll
    for (int j = 0; j < 4; ++j) o[i][j] = (f32x4){0.f, 0.f, 0.f, 0.f};
  float ssum[4] = {0.f, 0.f, 0.f, 0.f};

  for (int lc = 0; lc < 16; ++lc) {
    f32x4 accs[2][4];
#pragma unroll
    for (int mt = 0; mt < 2; ++mt)
#pragma unroll
      for (int nt = 0; nt < 4; ++nt) accs[mt][nt] = (f32x4){0.f, 0.f, 0.f, 0.f};
    {
      const unsigned short* pr =
          pjb + (((size_t)((lc * 8 + wv * 2) * 10)) << 9) + (lane << 3);
#pragma unroll
      for (int ks = 0; ks < 10; ++ks) {
        bf16x8 a0 = *(const bf16x8*)(pr + ((size_t)ks << 9));
        bf16x8 a1 = *(const bf16x8*)(pr + ((size_t)(10 + ks) << 9));
#pragma unroll
        for (int nt = 0; nt < 4; ++nt) {
          bf16x8 bb = *(const bf16x8*)&s_avgF[(((size_t)(ks * 4 + nt)) << 9) + (lane << 3)];
          accs[0][nt] = MFMA(a0, bb, accs[0][nt]);
          accs[1][nt] = MFMA(a1, bb, accs[1][nt]);
        }
      }
    }
    __syncthreads();  // prev PV done reading s_PF
#pragma unroll
    for (int nt = 0; nt < 4; ++nt) {
      float psum = 0.f;
#pragma unroll
      for (int mt = 0; mt < 2; ++mt) {
        const int lb = (lc << 7) + wv * 32 + mt * 16 + quad * 4;
        unsigned short u[4];
#pragma unroll
        for (int r = 0; r < 4; ++r) {
          float p = (lb + r < LP_) ? __expf(accs[mt][nt][r]) : 0.f;
          psum += p;
          u[r] = f2b(p);
        }
        int lane_P = (((mt << 1) | (quad >> 1)) << 4) + c16;
        *(ushort4*)&s_PF[(((size_t)(nt * 4 + wv)) << 9) + lane_P * 8 + ((quad & 1) << 2)] =
            make_ushort4(u[0], u[1], u[2], u[3]);
      }
      psum += __shfl_xor(psum, 16);
      psum += __shfl_xor(psum, 32);
      ssum[nt] += psum;
    }
    __syncthreads();  // s_PF visible
    {
      const unsigned short* cw =
          cFb + (((size_t)(wv * 4 * 64 + lc * 4)) << 9) + (lane << 3);
#pragma unroll
      for (int sub = 0; sub < 4; ++sub) {
        bf16x8 ap[4];
#pragma unroll
        for (int nt = 0; nt < 4; ++nt)
          ap[nt] = *(const bf16x8*)&s_PF[(((size_t)(nt * 4 + sub)) << 9) + (lane << 3)];
#pragma unroll
        for (int ft = 0; ft < 4; ++ft) {
          bf16x8 bb = *(const bf16x8*)(cw + (((size_t)(ft * 64 + sub)) << 9));
#pragma unroll
          for (int nt = 0; nt < 4; ++nt) o[nt][ft] = MFMA(ap[nt], bb, o[nt][ft]);
        }
      }
    }
  }

  if (lane < 16) {
#pragma unroll
    for (int nt = 0; nt < 4; ++nt) s_wsum[wv * 64 + nt * 16 + lane] = ssum[nt];
  }
  __syncthreads();
  if (tid < 64)
    s_sum[tid] = s_wsum[tid] + s_wsum[64 + tid] + s_wsum[128 + tid] + s_wsum[192 + tid];
  __syncthreads();
#pragma unroll
  for (int nt = 0; nt < 4; ++nt) {
    float inv4[4];
#pragma unroll
    for (int r = 0; r < 4; ++r) inv4[r] = 1.f / s_sum[nt * 16 + quad * 4 + r];
#pragma unroll
    for (int ft = 0; ft < 4; ++ft) {
      int f = wv * 64 + ft * 16 + c16;
      if (f < 224) {
        int kt = f >> 5;
        int qA = (f & 31) >> 3;
        int jA = f & 7;
#pragma unroll
        for (int r = 0; r < 4; ++r)
          s_AOF[(((size_t)(nt * 7 + kt)) << 9) + ((qA << 4) + quad * 4 + r) * 8 + jA] =
              f2b(o[nt][ft][r] * inv4[r]);
      }
    }
  }
  __syncthreads();
  float la[4][4];
#pragma unroll
  for (int nt = 0; nt < 4; ++nt)
#pragma unroll
    for (int r = 0; r < 4; ++r) la[nt][r] = 0.f;
#pragma unroll
  for (int i = 0; i < 8; ++i) {
    f32x4 pa[4];
#pragma unroll
    for (int nt = 0; nt < 4; ++nt) pa[nt] = (f32x4){0.f, 0.f, 0.f, 0.f};
    const unsigned short* wof = WoF + (((size_t)((wv * 8 + i) * 7)) << 9) + (lane << 3);
#pragma unroll
    for (int kt = 0; kt < 7; ++kt) {
      bf16x8 bw = *(const bf16x8*)(wof + ((size_t)kt << 9));
#pragma unroll
      for (int nt = 0; nt < 4; ++nt) {
        bf16x8 aa = *(const bf16x8*)&s_AOF[(((size_t)(nt * 7 + kt)) << 9) + (lane << 3)];
        pa[nt] = MFMA(aa, bw, pa[nt]);
      }
    }
    int feat = wv * 128 + i * 16 + c16;
    float bof = (feat < FEAT_) ? bo[feat] : 0.f;
#pragma unroll
    for (int nt = 0; nt < 4; ++nt) {
#pragma unroll
      for (int r = 0; r < 4; ++r) {
        int ng = n0 + nt * 16 + quad * 4 + r;
        float pv = fmaxf(pa[nt][r] + bof, 0.f);
        float gv = (feat < FEAT_) ? b2f(geb[(size_t)ng * 512 + feat]) : 0.f;
        la[nt][r] = fmaf(pv, gv, la[nt][r]);
      }
    }
  }
#pragma unroll
  for (int nt = 0; nt < 4; ++nt)
#pragma unroll
    for (int r = 0; r < 4; ++r) {
      float v = la[nt][r];
      v += __shfl_xor(v, 1); v += __shfl_xor(v, 2);
      v += __shfl_xor(v, 4); v += __shfl_xor(v, 8);
      if (c16 == 0) atomicAdd(&s_lg[nt * 16 + quad * 4 + r], v);
    }
  __syncthreads();
  if (tid < 64) {
    int ng = n0 + tid;
    if (ng < NL_) out[(size_t)b * NL_ + ng] = s_lg[tid];
  }
}

// ---------------------------------------------------------------------------
__global__ __launch_bounds__(1024) void k_loss(const float* __restrict__ lgts,
                                               const float* __restrict__ y,
                                               float* __restrict__ loss) {
  __shared__ float red[1024];
  const int tid = threadIdx.x;
  float s = 0.f;
  for (int i = tid; i < B_ * NL_; i += 1024) {
    float l = lgts[i], yy = y[i];
    s += fmaxf(l, 0.f) - l * yy + log1pf(expf(-fabsf(l)));
  }
  red[tid] = s;
  __syncthreads();
  for (int st = 512; st > 0; st >>= 1) {
    if (tid < st) red[tid] += red[tid + st];
    __syncthreads();
  }
  if (tid == 0) loss[0] = red[0] * (1.f / B_);
}

// ---------------------------------------------------------------------------
extern "C" void kernel_launch(void* const* d_in, const int* in_sizes, int n_in,
                              void* d_out, int out_size, void* d_ws, size_t ws_size,
                              hipStream_t stream) {
  const int*   x     = (const int*)  d_in[0];
  const float* y     = (const float*)d_in[1];
  const float* mask  = (const float*)d_in[2];
  const float* we    = (const float*)d_in[3];
  const int*   lidx  = (const int*)  d_in[4];
  const float* lmask = (const float*)d_in[5];
  const float* adj   = (const float*)d_in[6];
  const float* nnb   = (const float*)d_in[7];
  const float* Wg    = (const float*)d_in[8];
  const float* bg    = (const float*)d_in[9];
  const float* Wc    = (const float*)d_in[10];
  const float* bc    = (const float*)d_in[11];
  const float* Wp    = (const float*)d_in[12];
  const float* bp    = (const float*)d_in[13];
  const float* Wo    = (const float*)d_in[14];
  const float* bo    = (const float*)d_in[15];
  float* out = (float*)d_out;
  char* W = (char*)d_ws;

  unsigned short* pjF  = (unsigned short*)(W + 0);          // 10,485,760
  unsigned short* cF   = (unsigned short*)(W + 10485760);   //  8,388,608
  unsigned short* avgb = (unsigned short*)(W + 18874368);   //  5,734,400
  unsigned short* geb  = (unsigned short*)(W + 24608768);   //  9,175,040
  float*          agg  = (float*)(W + 33783808);            // 10,706,400
  unsigned short* WcF  = (unsigned short*)(W + 44490208);   //  1,638,400
  unsigned short* WpF  = (unsigned short*)(W + 46128608);   //    143,360
  unsigned short* WoF  = (unsigned short*)(W + 46271968);   //    229,376 (end 46,501,344)
  float*          avg  = (float*)(W + 0);                   // alias pjF+cF (dead until k_cpj)

  k_avg<<<(NLP_ * 80 + 255) / 256, 256, 0, stream>>>(we, lidx, lmask, avg, avgb, geb);
  k_agg<<<NL_, 256, 0, stream>>>(adj, avg, nnb, agg);
  k_gh<<<(NL_ + 7) / 8, 256, 0, stream>>>(agg, Wg, bg, geb);
  k_wct<<<(KW_ * 16 * 10 * 512 + 255) / 256, 256, 0, stream>>>(Wc, WcF);
  k_wpt<<<(20 * 7 * 512 + 255) / 256, 256, 0, stream>>>(Wp, WpF);
  k_wot<<<(32 * 7 * 512 + 255) / 256, 256, 0, stream>>>(Wo, WoF);
  k_cpj<<<dim3(32, B_), 256, 0, stream>>>(x, mask, we, WcF, bc, WpF, bp, cF, pjF);
  k_attn<<<140 * 8, 256, 0, stream>>>(pjF, cF, avgb, WoF, geb, bo, out);
  k_loss<<<1, 1024, 0, stream>>>(out, y, out + B_ * NL_);
}

// Round 6
// 1030.063 us; speedup vs baseline: 5.2069x; 1.2011x over previous
//
#include <hip/hip_runtime.h>
#include <math.h>

#define B_    8
#define L_    2000
#define V_    50000
#define E_    300
#define NL_   8922
#define NLP_  8960   // padded label count (multiple of 64)
#define LW_   10
#define F_    200
#define KW_   10
#define H_    200
#define FEAT_ 500
#define LP_   1991   // L - K + 1

typedef __attribute__((ext_vector_type(8))) short bf16x8;
typedef __attribute__((ext_vector_type(4))) float f32x4;

static __device__ __forceinline__ unsigned short f2b(float f) {
  unsigned u = __builtin_bit_cast(unsigned, f);
  u += 0x7FFF + ((u >> 16) & 1);   // round-to-nearest-even
  return (unsigned short)(u >> 16);
}
static __device__ __forceinline__ float b2f(unsigned short u) {
  unsigned v = ((unsigned)u) << 16;
  return __builtin_bit_cast(float, v);
}
static __device__ __forceinline__ float fast_tanh(float x) {
  x = fminf(fmaxf(x, -10.f), 10.f);
  float t = __expf(2.f * x);
  return (t - 1.f) / (t + 1.f);
}
// async global->LDS DMA, 16B/lane, zero result VGPRs. LDS dst = uniform base + lane*16.
static __device__ __forceinline__ void stage16(const void* g, void* l) {
  __builtin_amdgcn_global_load_lds(
      (const __attribute__((address_space(1))) unsigned int*)g,
      (__attribute__((address_space(3))) unsigned int*)l, 16, 0, 0);
}

#define MFMA(a, b, c) __builtin_amdgcn_mfma_f32_16x16x32_bf16(a, b, c, 0, 0, 0)

// Fragment conventions (mfma_f32_16x16x32_bf16, m89/m91-verified):
//   A[m][k]: m = lane&15, k = (lane>>4)*8 + j
//   B[n][k]: n = lane&15, k = (lane>>4)*8 + j
//   D[m][n]: m-row = (lane>>4)*4 + reg, n-col = lane&15
// Frag-major layout: tile*512 + lane*8 + j  -> wave load = 1 KB contiguous.

// ---------------------------------------------------------------------------
// avg fp32 [n][300] (for k_agg), avgb bf16 [n][320], geF bf16 D-frag-major
// geF[ntile(560)][ftile(32)][lane(64)][r(4)]: label = ntile*16+(lane>>4)*4+r,
// feat = ftile*16+(lane&15). Padding pre-zeroed by memset.
__global__ __launch_bounds__(256) void k_avg(const float* __restrict__ we,
                                             const int* __restrict__ lidx,
                                             const float* __restrict__ lmask,
                                             float* __restrict__ avg,
                                             unsigned short* __restrict__ avgb,
                                             unsigned short* __restrict__ geF) {
  int idx = blockIdx.x * 256 + threadIdx.x;
  if (idx >= NLP_ * 80) return;
  int n = idx / 80, e4 = idx - n * 80;
  if (n >= NL_ || e4 >= 75) {
    *(ushort4*)&avgb[(size_t)n * 320 + e4 * 4] = make_ushort4(0, 0, 0, 0);
    return;
  }
  float ax = 0.f, ay = 0.f, az = 0.f, aw = 0.f, ms = 0.f;
#pragma unroll
  for (int w = 0; w < LW_; ++w) {
    float mw = lmask[n * LW_ + w];
    const float4 f = *(const float4*)&we[(size_t)lidx[n * LW_ + w] * E_ + e4 * 4];
    ax = fmaf(f.x, mw, ax); ay = fmaf(f.y, mw, ay);
    az = fmaf(f.z, mw, az); aw = fmaf(f.w, mw, aw);
    ms += mw;
  }
  float inv = 1.f / ms;
  float4 v = {ax * inv, ay * inv, az * inv, aw * inv};
  *(float4*)&avg[(size_t)n * 300 + e4 * 4] = v;
  *(ushort4*)&avgb[(size_t)n * 320 + e4 * 4] =
      make_ushort4(f2b(v.x), f2b(v.y), f2b(v.z), f2b(v.w));
  // geF scatter (4 scalar stores)
  int ntg = n >> 4, quad = (n >> 2) & 3, r = n & 3;
  int ftg = (e4 * 4) >> 4, c0 = (e4 * 4) & 15;
  size_t tb = (((size_t)ntg * 32 + ftg) << 8);
  float vv[4] = {v.x, v.y, v.z, v.w};
#pragma unroll
  for (int t = 0; t < 4; ++t)
    geF[(tb + quad * 16 + c0 + t) * 4 + r] = f2b(vv[t]);
}

// ---------------------------------------------------------------------------
__global__ __launch_bounds__(256) void k_agg(const float* __restrict__ adj,
                                             const float* __restrict__ avg,
                                             const float* __restrict__ nnb,
                                             float* __restrict__ agg) {
  __shared__ int s_idx[1024];
  __shared__ float s_val[1024];
  __shared__ int s_cnt;
  const int n = blockIdx.x;
  const int tid = threadIdx.x;
  if (tid == 0) s_cnt = 0;
  __syncthreads();
  const float* row = adj + (size_t)n * NL_;
  for (int j = tid; j < NL_; j += 256) {
    float v = row[j];
    if (v != 0.f) {
      int p = atomicAdd(&s_cnt, 1);
      if (p < 1024) { s_idx[p] = j; s_val[p] = v; }
    }
  }
  __syncthreads();
  const int m = min(s_cnt, 1024);
  const float inv = 1.f / nnb[n];
  float a0 = 0.f, a1 = 0.f;
  for (int i = 0; i < m; ++i) {
    const float* ar = avg + (size_t)s_idx[i] * 300;
    float v = s_val[i];
    a0 = fmaf(v, ar[tid], a0);
    if (tid < E_ - 256) a1 = fmaf(v, ar[tid + 256], a1);
  }
  agg[(size_t)n * E_ + tid] = a0 * inv;
  if (tid < E_ - 256) agg[(size_t)n * E_ + tid + 256] = a1 * inv;
}

// ---------------------------------------------------------------------------
// gh -> geF feats 300..499 (bf16, D-frag-major)
__global__ __launch_bounds__(256) void k_gh(const float* __restrict__ agg,
                                            const float* __restrict__ Wg,
                                            const float* __restrict__ bg,
                                            unsigned short* __restrict__ geF) {
  __shared__ float s_agg[2400];  // [e][8]
  const int n0 = blockIdx.x * 8;
  const int tid = threadIdx.x;
  for (int i = tid; i < 2400; i += 256) {
    int e = i >> 3, nn = i & 7;
    int n = n0 + nn;
    s_agg[i] = (n < NL_) ? agg[(size_t)n * E_ + e] : 0.f;
  }
  __syncthreads();
  if (tid < H_) {
    const int h = tid;
    const int feat = 300 + h;
    float bb = bg[h];
    float acc[8];
#pragma unroll
    for (int i = 0; i < 8; ++i) acc[i] = bb;
    for (int e = 0; e < E_; ++e) {
      float w = Wg[(size_t)e * H_ + h];
      float4 a0 = *(const float4*)&s_agg[e * 8];
      float4 a1 = *(const float4*)&s_agg[e * 8 + 4];
      acc[0] = fmaf(a0.x, w, acc[0]); acc[1] = fmaf(a0.y, w, acc[1]);
      acc[2] = fmaf(a0.z, w, acc[2]); acc[3] = fmaf(a0.w, w, acc[3]);
      acc[4] = fmaf(a1.x, w, acc[4]); acc[5] = fmaf(a1.y, w, acc[5]);
      acc[6] = fmaf(a1.z, w, acc[6]); acc[7] = fmaf(a1.w, w, acc[7]);
    }
    const int ftg = feat >> 4, cc = feat & 15;
#pragma unroll
    for (int i = 0; i < 8; ++i) {
      int n = n0 + i;
      if (n < NL_) {
        size_t tb = (((size_t)(n >> 4) * 32 + ftg) << 8);
        geF[(tb + ((n >> 2) & 3) * 16 + cc) * 4 + (n & 3)] = f2b(fmaxf(acc[i], 0.f));
      }
    }
  }
}

// ---------------------------------------------------------------------------
// WcF frag-major: [koff(10)][ft(16)][ks(10)][512]
__global__ __launch_bounds__(256) void k_wct(const float* __restrict__ Wc,
                                             unsigned short* __restrict__ WcF) {
  int idx = blockIdx.x * 256 + threadIdx.x;
  if (idx >= KW_ * 16 * 10 * 512) return;
  int koff = idx / (16 * 10 * 512);
  int rem = idx - koff * (16 * 10 * 512);
  int ft = rem / (10 * 512);
  int rem2 = rem - ft * (10 * 512);
  int ks = rem2 >> 9;
  int t = rem2 & 511;
  int lane = t >> 3, j = t & 7;
  int f = ft * 16 + (lane & 15);
  int e = ks * 32 + (lane >> 4) * 8 + j;
  float v = (f < F_ && e < E_) ? Wc[((size_t)f * E_ + e) * KW_ + koff] : 0.f;
  WcF[idx] = f2b(v);
}

// ---------------------------------------------------------------------------
// WpF frag-major: [et(20)][kt(7)][512]
__global__ __launch_bounds__(256) void k_wpt(const float* __restrict__ Wp,
                                             unsigned short* __restrict__ WpF) {
  int idx = blockIdx.x * 256 + threadIdx.x;
  if (idx >= 20 * 7 * 512) return;
  int et = idx / (7 * 512);
  int rem = idx - et * (7 * 512);
  int kt = rem >> 9;
  int t = rem & 511;
  int lane = t >> 3, j = t & 7;
  int e = et * 16 + (lane & 15);
  int f = kt * 32 + (lane >> 4) * 8 + j;
  float v = (e < E_ && f < F_) ? Wp[(size_t)f * E_ + e] : 0.f;
  WpF[idx] = f2b(v);
}

// ---------------------------------------------------------------------------
// WoF frag-major: [g(32)][kt(7)][512]; feat = g*16 + (lane&15)
__global__ __launch_bounds__(256) void k_wot(const float* __restrict__ Wo,
                                             unsigned short* __restrict__ WoF) {
  int idx = blockIdx.x * 256 + threadIdx.x;
  if (idx >= 32 * 7 * 512) return;
  int g = idx / (7 * 512);
  int rem = idx - g * (7 * 512);
  int kt = rem >> 9;
  int t = rem & 511;
  int lane = t >> 3, j = t & 7;
  int feat = g * 16 + (lane & 15);
  int f = kt * 32 + (lane >> 4) * 8 + j;
  float v = (feat < FEAT_ && f < F_) ? Wo[(size_t)f * FEAT_ + feat] : 0.f;
  WoF[idx] = f2b(v);
}

// ---------------------------------------------------------------------------
// Fused conv + pj -> cF [b][ft2(16)][su(64)][512], pjF [b][lt(128)][ks(10)][512]
__global__ __launch_bounds__(256) void k_cpj(const int* __restrict__ x,
                                             const float* __restrict__ mask,
                                             const float* __restrict__ we,
                                             const unsigned short* __restrict__ WcF,
                                             const float* __restrict__ bc,
                                             const unsigned short* __restrict__ WpF,
                                             const float* __restrict__ bp,
                                             unsigned short* __restrict__ cF,
                                             unsigned short* __restrict__ pjF) {
  __shared__ __attribute__((aligned(16))) unsigned char smem[78896];
  unsigned short* s_xe  = (unsigned short*)smem;            // [73][344] 50224 B
  unsigned short* s_pjF = (unsigned short*)smem;            // [4][10][512] alias
  unsigned short* s_cA  = (unsigned short*)(smem + 50224);  // [4][7][512] 28672 B

  const int b = blockIdx.y;
  const int l0 = blockIdx.x * 64;
  const int tid = threadIdx.x;
  const int wv = tid >> 6, lane = tid & 63, quad = lane >> 4, c16 = lane & 15;

  for (int i = tid; i < 73 * 75; i += 256) {
    int row = i / 75, e4 = i - row * 75;
    int l = l0 + row;
    float4 v = {0.f, 0.f, 0.f, 0.f};
    if (l < L_) {
      int bl = b * L_ + l;
      v = *(const float4*)&we[(size_t)x[bl] * E_ + e4 * 4];
      float mm = mask[bl];
      v.x *= mm; v.y *= mm; v.z *= mm; v.w *= mm;
    }
    *(ushort4*)&s_xe[row * 344 + e4 * 4] =
        make_ushort4(f2b(v.x), f2b(v.y), f2b(v.z), f2b(v.w));
  }
  for (int i = tid; i < 73 * 5; i += 256) {
    int row = i / 5, c = i - row * 5;
    *(ushort4*)&s_xe[row * 344 + (75 + c) * 4] = make_ushort4(0, 0, 0, 0);
  }
  __syncthreads();

  f32x4 acc[4][4];
#pragma unroll
  for (int mt = 0; mt < 4; ++mt)
#pragma unroll
    for (int j = 0; j < 4; ++j) acc[mt][j] = (f32x4){0.f, 0.f, 0.f, 0.f};
  for (int koff = 0; koff < KW_; ++koff) {
#pragma unroll
    for (int ks = 0; ks < 10; ++ks) {
      bf16x8 a[4];
#pragma unroll
      for (int mt = 0; mt < 4; ++mt)
        a[mt] = *(const bf16x8*)&s_xe[(mt * 16 + c16 + koff) * 344 + ks * 32 + quad * 8];
#pragma unroll
      for (int jj = 0; jj < 4; ++jj) {
        bf16x8 bw = *(const bf16x8*)
            &WcF[(((size_t)((koff * 16 + wv * 4 + jj) * 10 + ks)) << 9) + (lane << 3)];
#pragma unroll
        for (int mt = 0; mt < 4; ++mt) acc[mt][jj] = MFMA(a[mt], bw, acc[mt][jj]);
      }
    }
  }
  unsigned short* cFb = cF + (size_t)b * (16 * 64 * 512);
#pragma unroll
  for (int jj = 0; jj < 4; ++jj) {
    const int ft2 = wv * 4 + jj;
    const int f = ft2 * 16 + c16;
    const float bcv = (f < F_) ? bc[f] : 0.f;
    const int kt = ft2 >> 1;
    const int qA = ((ft2 & 1) << 1) | (c16 >> 3);
    const int jA = c16 & 7;
#pragma unroll
    for (int mt = 0; mt < 4; ++mt) {
      unsigned short u[4];
#pragma unroll
      for (int r = 0; r < 4; ++r) u[r] = f2b(fmaxf(acc[mt][jj][r] + bcv, 0.f));
      int su = (l0 >> 5) + (mt >> 1);
      int lane_c = ((((mt & 1) << 1) | (quad >> 1)) << 4) + c16;
      *(ushort4*)&cFb[(((size_t)(ft2 * 64 + su)) << 9) + lane_c * 8 + ((quad & 1) << 2)] =
          make_ushort4(u[0], u[1], u[2], u[3]);
      if (ft2 < 14) {
#pragma unroll
        for (int r = 0; r < 4; ++r)
          s_cA[(((size_t)(mt * 7 + kt)) << 9) + ((qA << 4) + quad * 4 + r) * 8 + jA] = u[r];
      }
    }
  }
  __syncthreads();

  f32x4 pacc[4][5];
#pragma unroll
  for (int mt = 0; mt < 4; ++mt)
#pragma unroll
    for (int j = 0; j < 5; ++j) pacc[mt][j] = (f32x4){0.f, 0.f, 0.f, 0.f};
#pragma unroll
  for (int kt = 0; kt < 7; ++kt) {
    bf16x8 a[4];
#pragma unroll
    for (int mt = 0; mt < 4; ++mt)
      a[mt] = *(const bf16x8*)&s_cA[(((size_t)(mt * 7 + kt)) << 9) + (lane << 3)];
#pragma unroll
    for (int j = 0; j < 5; ++j) {
      bf16x8 bw = *(const bf16x8*)
          &WpF[(((size_t)((wv * 5 + j) * 7 + kt)) << 9) + (lane << 3)];
#pragma unroll
      for (int mt = 0; mt < 4; ++mt) pacc[mt][j] = MFMA(a[mt], bw, pacc[mt][j]);
    }
  }
  __syncthreads();  // s_xe dead -> s_pjF alias safe
#pragma unroll
  for (int j = 0; j < 5; ++j) {
    const int et = wv * 5 + j;
    const int e = et * 16 + c16;
    const float bpe = (e < E_) ? bp[e] : 0.f;
    const int ks = et >> 1;
    const int qP = ((et & 1) << 1) | (c16 >> 3);
    const int jP = c16 & 7;
#pragma unroll
    for (int mt = 0; mt < 4; ++mt) {
#pragma unroll
      for (int r = 0; r < 4; ++r) {
        float v = (e < E_) ? fast_tanh(pacc[mt][j][r] + bpe) : 0.f;
        s_pjF[(((size_t)(mt * 10 + ks)) << 9) + ((qP << 4) + quad * 4 + r) * 8 + jP] = f2b(v);
      }
    }
  }
  __syncthreads();
  {
    unsigned short* dst = pjF + (((size_t)((b * 128 + (l0 >> 4)) * 10)) << 9);
    for (int i = tid; i < 2560; i += 256)
      *(uint4*)&dst[i * 8] = *(const uint4*)&s_pjF[i * 8];
  }
}

// ---------------------------------------------------------------------------
// Fused attention + proj + logits. 64 labels/block, waves split labels (16 ea).
// l-chunk 32, double-buffered global_load_lds staging, ONE barrier per chunk.
__global__ __launch_bounds__(256, 2) void k_attn(
    const unsigned short* __restrict__ pjF,   // [8][128][10][512]
    const unsigned short* __restrict__ cF,    // [8][16][64][512]
    const unsigned short* __restrict__ avgb,  // [8960][320]
    const unsigned short* __restrict__ WoF,   // [32][7][512]
    const unsigned short* __restrict__ geF,   // [560][32][64][4] bf16 D-frag
    const float* __restrict__ bo,
    float* __restrict__ out) {
  __shared__ __attribute__((aligned(16))) unsigned char smem[74240];
  // buf0 @0, buf1 @34816 (each: pj 20480 B + cF 14336 B)
  // P @69632 (1 KB/wave), s_sum @73728, s_lg @73984; AO aliases buf0 (28672 B)
  unsigned short* Ps  = (unsigned short*)(smem + 69632);
  float* s_sum = (float*)(smem + 73728);
  float* s_lg  = (float*)(smem + 73984);
  unsigned short* AOs = (unsigned short*)smem;

  const int tid = threadIdx.x;
  const int b  = blockIdx.x & 7;               // XCD-locality swizzle
  const int n0 = (blockIdx.x >> 3) << 6;
  const int wv = tid >> 6, lane = tid & 63, quad = lane >> 4, c16 = lane & 15;

  if (tid < 64) s_lg[tid] = 0.f;

  // avg B-frags in regs for this wave's 16 labels (nt = wv)
  bf16x8 bavg[10];
  {
    const unsigned short* ab = avgb + (size_t)(n0 + wv * 16 + c16) * 320 + quad * 8;
#pragma unroll
    for (int ks = 0; ks < 10; ++ks) bavg[ks] = *(const bf16x8*)(ab + ks * 32);
  }

  const unsigned short* pjb = pjF + (size_t)b * (128 * 10 * 512);
  const unsigned short* cFb = cF + (size_t)b * (16 * 64 * 512);

  // stage chunk 0 into buf0
  {
    const unsigned char* pg = (const unsigned char*)pjb;
#pragma unroll
    for (int t = 0; t < 5; ++t) {
      int off = (wv * 5 + t) << 10;
      stage16(pg + off + lane * 16, smem + off);
    }
#pragma unroll
    for (int t = 0; t < 4; ++t) {
      int ft = wv + t * 4;
      if (ft < 14)
        stage16((const unsigned char*)cFb + (((size_t)(ft * 64)) << 10) + lane * 16,
                smem + 20480 + (ft << 10));
    }
  }

  f32x4 o[14];
#pragma unroll
  for (int i = 0; i < 14; ++i) o[i] = (f32x4){0.f, 0.f, 0.f, 0.f};
  float ssum = 0.f;

  for (int lc = 0; lc < 64; ++lc) {
    __builtin_amdgcn_s_waitcnt(0);   // staged loads for buf[lc&1] landed
    __syncthreads();                 // all waves' stages visible; prior reads done
    unsigned char* cur = smem + ((lc & 1) ? 34816 : 0);
    unsigned char* nxt = smem + ((lc & 1) ? 0 : 34816);
    if (lc + 1 < 64) {               // fire-and-forget stage of next chunk
      const unsigned char* pg =
          (const unsigned char*)pjb + (((size_t)((lc + 1) * 20)) << 10);
#pragma unroll
      for (int t = 0; t < 5; ++t) {
        int off = (wv * 5 + t) << 10;
        stage16(pg + off + lane * 16, nxt + off);
      }
#pragma unroll
      for (int t = 0; t < 4; ++t) {
        int ft = wv + t * 4;
        if (ft < 14)
          stage16((const unsigned char*)cFb + (((size_t)(ft * 64 + lc + 1)) << 10) + lane * 16,
                  nxt + 20480 + (ft << 10));
      }
    }
    // ---- scores: A = pj (LDS), B = avg (regs). 20 MFMA ----
    const unsigned short* pt = (const unsigned short*)cur;
    f32x4 acc0 = (f32x4){0.f, 0.f, 0.f, 0.f};
    f32x4 acc1 = (f32x4){0.f, 0.f, 0.f, 0.f};
#pragma unroll
    for (int ks = 0; ks < 10; ++ks) {
      bf16x8 a0 = *(const bf16x8*)(pt + (ks << 9) + (lane << 3));
      bf16x8 a1 = *(const bf16x8*)(pt + ((10 + ks) << 9) + (lane << 3));
      acc0 = MFMA(a0, bavg[ks], acc0);
      acc1 = MFMA(a1, bavg[ks], acc1);
    }
    // ---- exp (bounded; no max) -> wave-private P (A-frag), reg sums ----
    float psum = 0.f;
#pragma unroll
    for (int lt = 0; lt < 2; ++lt) {
      f32x4 av = lt ? acc1 : acc0;
      int lb = (lc << 5) + lt * 16 + quad * 4;
      unsigned short u[4];
#pragma unroll
      for (int r = 0; r < 4; ++r) {
        float p = (lb + r < LP_) ? __expf(av[r]) : 0.f;
        psum += p;
        u[r] = f2b(p);
      }
      *(ushort4*)&Ps[(wv << 9) + (((lt * 2 + (quad >> 1)) * 16 + c16) << 3) +
                     ((quad & 1) << 2)] = make_ushort4(u[0], u[1], u[2], u[3]);
    }
    psum += __shfl_xor(psum, 16);
    psum += __shfl_xor(psum, 32);
    ssum += psum;
    // ---- PV: A = own P (LDS, no barrier), B = cF tile (LDS). 14 MFMA ----
    {
      bf16x8 aP = *(const bf16x8*)&Ps[(wv << 9) + (lane << 3)];
      const unsigned short* cc = (const unsigned short*)(cur + 20480);
#pragma unroll
      for (int ft = 0; ft < 14; ++ft) {
        bf16x8 bC = *(const bf16x8*)(cc + (ft << 9) + (lane << 3));
        o[ft] = MFMA(aP, bC, o[ft]);
      }
    }
  }

  // ---- normalize -> AO (A-frag, per-nt region in buf0 alias) ----
  if (lane < 16) s_sum[wv * 16 + lane] = ssum;   // wave-local
  {
    float inv4[4];
#pragma unroll
    for (int r = 0; r < 4; ++r) inv4[r] = 1.f / s_sum[wv * 16 + quad * 4 + r];
#pragma unroll
    for (int ft = 0; ft < 14; ++ft) {
      int kt = ft >> 1;
      int quadA = ((ft & 1) << 1) | (c16 >> 3);
      int jA = c16 & 7;
#pragma unroll
      for (int r = 0; r < 4; ++r)
        AOs[wv * 3584 + (kt << 9) + (quadA * 16 + quad * 4 + r) * 8 + jA] =
            f2b(o[ft][r] * inv4[r]);
    }
  }
  __syncthreads();
  // ---- proj: waves split feat (8 tiles each); A = AO all nt (LDS) ----
  float la[4][4];
#pragma unroll
  for (int nt = 0; nt < 4; ++nt)
#pragma unroll
    for (int r = 0; r < 4; ++r) la[nt][r] = 0.f;
#pragma unroll
  for (int i = 0; i < 8; ++i) {
    const int ftg = wv * 8 + i;
    const int feat = (ftg << 4) + c16;
    f32x4 pa[4];
#pragma unroll
    for (int nt = 0; nt < 4; ++nt) pa[nt] = (f32x4){0.f, 0.f, 0.f, 0.f};
    const unsigned short* wof = WoF + (((size_t)(ftg * 7)) << 9) + (lane << 3);
#pragma unroll
    for (int kt = 0; kt < 7; ++kt) {
      bf16x8 bw = *(const bf16x8*)(wof + (kt << 9));
#pragma unroll
      for (int nt = 0; nt < 4; ++nt) {
        bf16x8 aa = *(const bf16x8*)&AOs[nt * 3584 + (kt << 9) + (lane << 3)];
        pa[nt] = MFMA(aa, bw, pa[nt]);
      }
    }
    const float bof = (feat < FEAT_) ? bo[feat] : 0.f;
#pragma unroll
    for (int nt = 0; nt < 4; ++nt) {
      ushort4 g4 = *(const ushort4*)
          &geF[((((size_t)(n0 >> 4) + nt) * 32 + ftg) << 8) + (lane << 2)];
      float gv[4] = {b2f(g4.x), b2f(g4.y), b2f(g4.z), b2f(g4.w)};
#pragma unroll
      for (int r = 0; r < 4; ++r) {
        float pv = fmaxf(pa[nt][r] + bof, 0.f);
        la[nt][r] = fmaf(pv, gv[r], la[nt][r]);   // geF zero-padded beyond FEAT/NL
      }
    }
  }
#pragma unroll
  for (int nt = 0; nt < 4; ++nt)
#pragma unroll
    for (int r = 0; r < 4; ++r) {
      float v = la[nt][r];
      v += __shfl_xor(v, 1); v += __shfl_xor(v, 2);
      v += __shfl_xor(v, 4); v += __shfl_xor(v, 8);
      if (c16 == 0) atomicAdd(&s_lg[nt * 16 + quad * 4 + r], v);
    }
  __syncthreads();
  if (tid < 64) {
    int ng = n0 + tid;
    if (ng < NL_) out[(size_t)b * NL_ + ng] = s_lg[tid];
  }
}

// ---------------------------------------------------------------------------
__global__ __launch_bounds__(1024) void k_loss(const float* __restrict__ lgts,
                                               const float* __restrict__ y,
                                               float* __restrict__ loss) {
  __shared__ float red[1024];
  const int tid = threadIdx.x;
  float s = 0.f;
  for (int i = tid; i < B_ * NL_; i += 1024) {
    float l = lgts[i], yy = y[i];
    s += fmaxf(l, 0.f) - l * yy + log1pf(expf(-fabsf(l)));
  }
  red[tid] = s;
  __syncthreads();
  for (int st = 512; st > 0; st >>= 1) {
    if (tid < st) red[tid] += red[tid + st];
    __syncthreads();
  }
  if (tid == 0) loss[0] = red[0] * (1.f / B_);
}

// ---------------------------------------------------------------------------
extern "C" void kernel_launch(void* const* d_in, const int* in_sizes, int n_in,
                              void* d_out, int out_size, void* d_ws, size_t ws_size,
                              hipStream_t stream) {
  const int*   x     = (const int*)  d_in[0];
  const float* y     = (const float*)d_in[1];
  const float* mask  = (const float*)d_in[2];
  const float* we    = (const float*)d_in[3];
  const int*   lidx  = (const int*)  d_in[4];
  const float* lmask = (const float*)d_in[5];
  const float* adj   = (const float*)d_in[6];
  const float* nnb   = (const float*)d_in[7];
  const float* Wg    = (const float*)d_in[8];
  const float* bg    = (const float*)d_in[9];
  const float* Wc    = (const float*)d_in[10];
  const float* bc    = (const float*)d_in[11];
  const float* Wp    = (const float*)d_in[12];
  const float* bp    = (const float*)d_in[13];
  const float* Wo    = (const float*)d_in[14];
  const float* bo    = (const float*)d_in[15];
  float* out = (float*)d_out;
  char* W = (char*)d_ws;

  unsigned short* pjF  = (unsigned short*)(W + 0);          // 10,485,760
  unsigned short* cF   = (unsigned short*)(W + 10485760);   //  8,388,608
  unsigned short* avgb = (unsigned short*)(W + 18874368);   //  5,734,400
  unsigned short* geF  = (unsigned short*)(W + 24608768);   //  9,175,040
  float*          agg  = (float*)(W + 33783808);            // 10,706,400
  unsigned short* WcF  = (unsigned short*)(W + 44490208);   //  1,638,400
  unsigned short* WpF  = (unsigned short*)(W + 46128608);   //    143,360
  unsigned short* WoF  = (unsigned short*)(W + 46271968);   //    229,376 (end 46,501,344)
  float*          avg  = (float*)(W + 0);  // fp32 [NL][300], aliases pjF+cF (dead before k_cpj)

  hipMemsetAsync(geF, 0, 9175040, stream);   // zero-pad labels>=NL, feats>=500
  k_avg<<<(NLP_ * 80 + 255) / 256, 256, 0, stream>>>(we, lidx, lmask, avg, avgb, geF);
  k_agg<<<NL_, 256, 0, stream>>>(adj, avg, nnb, agg);
  k_gh<<<(NL_ + 7) / 8, 256, 0, stream>>>(agg, Wg, bg, geF);
  k_wct<<<(KW_ * 16 * 10 * 512 + 255) / 256, 256, 0, stream>>>(Wc, WcF);
  k_wpt<<<(20 * 7 * 512 + 255) / 256, 256, 0, stream>>>(Wp, WpF);
  k_wot<<<(32 * 7 * 512 + 255) / 256, 256, 0, stream>>>(Wo, WoF);
  k_cpj<<<dim3(32, B_), 256, 0, stream>>>(x, mask, we, WcF, bc, WpF, bp, cF, pjF);
  k_attn<<<140 * 8, 256, 0, stream>>>(pjF, cF, avgb, WoF, geF, bo, out);
  k_loss<<<1, 1024, 0, stream>>>(out, y, out + B_ * NL_);
}